// Round 14
// baseline (449.353 us; speedup 1.0000x reference)
//
#include <hip/hip_runtime.h>
#include <hip/hip_fp16.h>

// UnifiedTransformerBlock on MI355X.
// R9/R13+: MoE GEMMs get T14 prefetch (issue next K-tile's global loads into
// registers before the MFMA phase; raw s_barrier + lgkmcnt(0)-only so loads
// stay in flight — R7 proved this barrier discipline correct; R7's regression
// was the QKV kernel spilling, so k_gemm_pk is left at the R6 k-loop).
// R8's 64-row split REVERTED: occupancy 26->51% gave no speedup and doubled
// FETCH (47->94MB) -> occupancy was not the limiter; exposed load latency is.

typedef _Float16 half8 __attribute__((ext_vector_type(8)));
typedef float f32x4 __attribute__((ext_vector_type(4)));

#define DI __device__ __forceinline__
#define BARRIER() asm volatile("s_barrier" ::: "memory")
#define WAIT_LGKM0() asm volatile("s_waitcnt lgkmcnt(0)" ::: "memory")

struct Desc { int e, base, rows; };

DI float blockReduceSum(float v, float* red) {
#pragma unroll
    for (int m = 32; m; m >>= 1) v += __shfl_xor(v, m);
    int w = threadIdx.x >> 6;
    if ((threadIdx.x & 63) == 0) red[w] = v;
    __syncthreads();
    v = red[0] + red[1] + red[2] + red[3];
    __syncthreads();
    return v;
}

DI void split2(float v, __half& hi, __half& lo) {
    hi = __float2half(v);
    lo = __float2half((v - __half2float(hi)) * 2048.0f);
}

// ---------- split-fp16 plane GEMM: C = A(MxK) * B^T(NxK) ----------
enum { EPI_RESID = 0, EPI_QKV = 1 };

template<int WM, int WN, int FM, int FN, int EPI>
__global__ __launch_bounds__(256, 2)
void k_gemm_pk(const __half* __restrict__ Ah, const __half* __restrict__ Al, int lda,
               const __half* __restrict__ Bh, const __half* __restrict__ Bl, int ldb,
               float* __restrict__ Cf, int ldc, int M, int N, int K,
               const float* __restrict__ resid,
               __half* __restrict__ qh_p, __half* __restrict__ ql_p,
               __half* __restrict__ kh_p, __half* __restrict__ kl_p,
               __half* __restrict__ vth_p, __half* __restrict__ vtl_p,
               const float* __restrict__ rc, const float* __restrict__ rs)
{
    constexpr int BM = WM * FM * 16, BN = WN * FN * 16;
    constexpr int PITCH = 40;                  // halves: 32 + 8 pad
    __shared__ __half AsH[BM * PITCH], AsL[BM * PITCH];
    __shared__ __half BsH[BN * PITCH], BsL[BN * PITCH];
    const int tid = threadIdx.x;
    const int lane = tid & 63, w = tid >> 6;
    const int l15 = lane & 15, g = lane >> 4;
    const int wm = w / WN, wn = w % WN;
    const int m0 = blockIdx.x * BM, n0 = blockIdx.y * BN;

    f32x4 acc0[FM][FN] = {}; f32x4 acc1[FM][FN] = {};

    for (int k0 = 0; k0 < K; k0 += 32) {
        __syncthreads();
#pragma unroll
        for (int it = 0; it < BM / 64; ++it) {
            int c = it * 256 + tid, row = c >> 2, kg = c & 3;
            long src = (long)(m0 + row) * lda + k0 + kg * 8;
            *(uint4*)&AsH[row * PITCH + kg * 8] = *(const uint4*)(Ah + src);
            *(uint4*)&AsL[row * PITCH + kg * 8] = *(const uint4*)(Al + src);
        }
#pragma unroll
        for (int it = 0; it < BN / 64; ++it) {
            int c = it * 256 + tid, row = c >> 2, kg = c & 3;
            long src = (long)(n0 + row) * ldb + k0 + kg * 8;
            *(uint4*)&BsH[row * PITCH + kg * 8] = *(const uint4*)(Bh + src);
            *(uint4*)&BsL[row * PITCH + kg * 8] = *(const uint4*)(Bl + src);
        }
        __syncthreads();
        half8 ah[FM], al[FM];
#pragma unroll
        for (int i = 0; i < FM; ++i) {
            int ar = (wm * FM * 16 + i * 16 + l15) * PITCH + g * 8;
            ah[i] = *(const half8*)&AsH[ar];
            al[i] = *(const half8*)&AsL[ar];
        }
#pragma unroll
        for (int n = 0; n < FN; ++n) {
            int br = (wn * FN * 16 + n * 16 + l15) * PITCH + g * 8;
            half8 bh = *(const half8*)&BsH[br];
            half8 bl = *(const half8*)&BsL[br];
#pragma unroll
            for (int i = 0; i < FM; ++i) {
                acc0[i][n] = __builtin_amdgcn_mfma_f32_16x16x32_f16(ah[i], bh, acc0[i][n], 0, 0, 0);
                acc1[i][n] = __builtin_amdgcn_mfma_f32_16x16x32_f16(ah[i], bl, acc1[i][n], 0, 0, 0);
                acc1[i][n] = __builtin_amdgcn_mfma_f32_16x16x32_f16(al[i], bh, acc1[i][n], 0, 0, 0);
            }
        }
    }

#pragma unroll
    for (int i = 0; i < FM; ++i)
#pragma unroll
    for (int n = 0; n < FN; ++n)
#pragma unroll
    for (int j = 0; j < 4; ++j) {
        float v = acc0[i][n][j] + acc1[i][n][j] * (1.0f / 2048.0f);
        int gm = m0 + wm * FM * 16 + i * 16 + g * 4 + j;
        int gn = n0 + wn * FN * 16 + n * 16 + l15;
        if constexpr (EPI == EPI_RESID) {
            Cf[(long)gm * ldc + gn] = v + resid[(long)gm * ldc + gn];
        } else {
            // QKV epilogue: RoPE for q/k, transpose-scatter for v, split planes.
            int t = gm & 1023, b = gm >> 10;
            float vp = __shfl_xor(v, 1);       // pair column (uniform control flow)
            if (gn < 2048) {
                int col = gn & 1023;
                int i2 = (col & 63) >> 1;
                float cv = rc[t * 32 + i2], sv = rs[t * 32 + i2];
                float rot = cv * v + sv * ((lane & 1) ? vp : -vp);
                __half hi_, lo_; split2(rot, hi_, lo_);
                long o = ((long)(b * 16 + (col >> 6)) * 1024 + t) * 64 + (col & 63);
                if (gn < 1024) { qh_p[o] = hi_; ql_p[o] = lo_; }
                else           { kh_p[o] = hi_; kl_p[o] = lo_; }
            } else {
                int col = gn - 2048;
                __half hi_, lo_; split2(v, hi_, lo_);
                long o = ((long)(b * 16 + (col >> 6)) * 64 + (col & 63)) * 1024 + t;
                vth_p[o] = hi_; vtl_p[o] = lo_;
            }
        }
    }
}

// ---------- flash attention, split-fp16 planes ----------
__global__ __launch_bounds__(256, 2)
void k_flash(const __half* __restrict__ qh_g, const __half* __restrict__ ql_g,
             const __half* __restrict__ kh_g, const __half* __restrict__ kl_g,
             const __half* __restrict__ vth_g, const __half* __restrict__ vtl_g,
             __half* __restrict__ oh_g, __half* __restrict__ ol_g)
{
    constexpr int P = 72;
    __shared__ __half KsH[64 * P], KsL[64 * P], VsH[64 * P], VsL[64 * P], PsH[64 * P], PsL[64 * P];
    const int tid = threadIdx.x, lane = tid & 63, w = tid >> 6;
    const int l15 = lane & 15, g = lane >> 4;
    const int q0 = blockIdx.x * 64;
    const int bh = blockIdx.y;
    const long base = (long)bh * 65536;

    half8 qhi[2], qlo[2];
    {
        long qoff = base + (long)(q0 + w * 16 + l15) * 64 + g * 8;
        qhi[0] = *(const half8*)(qh_g + qoff); qhi[1] = *(const half8*)(qh_g + qoff + 32);
        qlo[0] = *(const half8*)(ql_g + qoff); qlo[1] = *(const half8*)(ql_g + qoff + 32);
    }

    float m_[4] = {-1e30f, -1e30f, -1e30f, -1e30f};
    float l_[4] = {0.f, 0.f, 0.f, 0.f};
    f32x4 o0[4] = {}, o1[4] = {};

    for (int kt = 0; kt < 16; ++kt) {
        __syncthreads();
#pragma unroll
        for (int it = 0; it < 2; ++it) {
            int c = it * 256 + tid, row = c >> 3, kg = c & 7;
            long src = base + (long)(kt * 64 + row) * 64 + kg * 8;
            *(uint4*)&KsH[row * P + kg * 8] = *(const uint4*)(kh_g + src);
            *(uint4*)&KsL[row * P + kg * 8] = *(const uint4*)(kl_g + src);
            long vs = base + (long)row * 1024 + kt * 64 + kg * 8;
            *(uint4*)&VsH[row * P + kg * 8] = *(const uint4*)(vth_g + vs);
            *(uint4*)&VsL[row * P + kg * 8] = *(const uint4*)(vtl_g + vs);
        }
        __syncthreads();

        f32x4 s0[4] = {}, s1[4] = {};
#pragma unroll
        for (int cf = 0; cf < 4; ++cf) {
            int kr = (cf * 16 + l15) * P + g * 8;
            half8 kh0 = *(const half8*)&KsH[kr], kh1 = *(const half8*)&KsH[kr + 32];
            half8 kl0 = *(const half8*)&KsL[kr], kl1 = *(const half8*)&KsL[kr + 32];
            s0[cf] = __builtin_amdgcn_mfma_f32_16x16x32_f16(qhi[0], kh0, s0[cf], 0, 0, 0);
            s1[cf] = __builtin_amdgcn_mfma_f32_16x16x32_f16(qhi[0], kl0, s1[cf], 0, 0, 0);
            s1[cf] = __builtin_amdgcn_mfma_f32_16x16x32_f16(qlo[0], kh0, s1[cf], 0, 0, 0);
            s0[cf] = __builtin_amdgcn_mfma_f32_16x16x32_f16(qhi[1], kh1, s0[cf], 0, 0, 0);
            s1[cf] = __builtin_amdgcn_mfma_f32_16x16x32_f16(qhi[1], kl1, s1[cf], 0, 0, 0);
            s1[cf] = __builtin_amdgcn_mfma_f32_16x16x32_f16(qlo[1], kh1, s1[cf], 0, 0, 0);
        }

#pragma unroll
        for (int j = 0; j < 4; ++j) {
            float sv[4];
#pragma unroll
            for (int cf = 0; cf < 4; ++cf)
                sv[cf] = (s0[cf][j] + s1[cf][j] * (1.0f / 2048.0f)) * 0.125f;
            float mx = fmaxf(fmaxf(sv[0], sv[1]), fmaxf(sv[2], sv[3]));
#pragma unroll
            for (int msk = 8; msk; msk >>= 1) mx = fmaxf(mx, __shfl_xor(mx, msk));
            float mn = fmaxf(m_[j], mx);
            float r = expf(m_[j] - mn);
            m_[j] = mn;
            float rs = 0.f;
#pragma unroll
            for (int cf = 0; cf < 4; ++cf) {
                float p = expf(sv[cf] - mn);
                rs += p;
                __half hi_, lo_; split2(p, hi_, lo_);
                PsH[(w * 16 + g * 4 + j) * P + cf * 16 + l15] = hi_;
                PsL[(w * 16 + g * 4 + j) * P + cf * 16 + l15] = lo_;
            }
#pragma unroll
            for (int msk = 8; msk; msk >>= 1) rs += __shfl_xor(rs, msk);
            l_[j] = l_[j] * r + rs;
#pragma unroll
            for (int df = 0; df < 4; ++df) { o0[df][j] *= r; o1[df][j] *= r; }
        }
        __syncthreads();

        int pr = (w * 16 + l15) * P + g * 8;
        half8 ph0 = *(const half8*)&PsH[pr], ph1 = *(const half8*)&PsH[pr + 32];
        half8 pl0 = *(const half8*)&PsL[pr], pl1 = *(const half8*)&PsL[pr + 32];
#pragma unroll
        for (int df = 0; df < 4; ++df) {
            int vr = (df * 16 + l15) * P + g * 8;
            half8 vh0 = *(const half8*)&VsH[vr], vh1 = *(const half8*)&VsH[vr + 32];
            half8 vl0 = *(const half8*)&VsL[vr], vl1 = *(const half8*)&VsL[vr + 32];
            o0[df] = __builtin_amdgcn_mfma_f32_16x16x32_f16(ph0, vh0, o0[df], 0, 0, 0);
            o1[df] = __builtin_amdgcn_mfma_f32_16x16x32_f16(ph0, vl0, o1[df], 0, 0, 0);
            o1[df] = __builtin_amdgcn_mfma_f32_16x16x32_f16(pl0, vh0, o1[df], 0, 0, 0);
            o0[df] = __builtin_amdgcn_mfma_f32_16x16x32_f16(ph1, vh1, o0[df], 0, 0, 0);
            o1[df] = __builtin_amdgcn_mfma_f32_16x16x32_f16(ph1, vl1, o1[df], 0, 0, 0);
            o1[df] = __builtin_amdgcn_mfma_f32_16x16x32_f16(pl1, vh1, o1[df], 0, 0, 0);
        }
    }

    float invl[4];
#pragma unroll
    for (int j = 0; j < 4; ++j) invl[j] = 1.0f / l_[j];
    const int b = bh >> 4, hh = bh & 15;
#pragma unroll
    for (int df = 0; df < 4; ++df)
#pragma unroll
    for (int j = 0; j < 4; ++j) {
        float v = (o0[df][j] + o1[df][j] * (1.0f / 2048.0f)) * invl[j];
        long orow = (long)b * 1024 + q0 + w * 16 + g * 4 + j;
        int col = hh * 64 + df * 16 + l15;
        __half hi_, lo_; split2(v, hi_, lo_);
        oh_g[orow * 1024 + col] = hi_;
        ol_g[orow * 1024 + col] = lo_;
    }
}

// ---------- one-time weight convert: fp32 [R][C] -> fp16 [C][R] ----------
__global__ __launch_bounds__(256) void k_wconv(const float* __restrict__ src,
                                               __half* __restrict__ dst, int R, int C)
{
    src += (long)blockIdx.z * R * C;
    dst += (long)blockIdx.z * R * C;
    __shared__ float t[64][65];
    const int tid = threadIdx.x;
    const int c0 = blockIdx.x * 64, r0 = blockIdx.y * 64;
#pragma unroll
    for (int it = 0; it < 4; ++it) {
        int idx = it * 256 + tid;
        int r = idx >> 4, c4 = (idx & 15) * 4;
        float4 v = *(const float4*)(src + (long)(r0 + r) * C + c0 + c4);
        t[r][c4] = v.x; t[r][c4 + 1] = v.y; t[r][c4 + 2] = v.z; t[r][c4 + 3] = v.w;
    }
    __syncthreads();
#pragma unroll
    for (int it = 0; it < 2; ++it) {
        int idx = it * 256 + tid;
        int orow = idx >> 3, oc = (idx & 7) * 8;
        __half v[8];
#pragma unroll
        for (int j = 0; j < 8; ++j) v[j] = __float2half(t[oc + j][orow]);
        *(uint4*)(dst + (long)(c0 + orow) * R + r0 + oc) = *(uint4*)v;
    }
}

// ---------- MoE grouped GEMM, B = fp16 transposed weights [n][k] ----------
// MODE 0: GEMM1 — B rows remapped (h1/h2 16-col pairing), SiLU fused, fp16 out.
// MODE 1: GEMM2 — straight rows, f32 out.
// T14 prefetch: next K-tile's global loads issued before the MFMA phase;
// raw s_barrier + lgkmcnt(0)-only keeps them in flight (no vmcnt(0) drain).
template<bool GATHER, int MODE, int FM, int FN, int WN>
__global__ __launch_bounds__(256, 2)
void k_gemm_moe(const __half* __restrict__ A, int lda, const int* __restrict__ rowidx,
                const Desc* __restrict__ desc, const int* __restrict__ ntiles,
                const __half* __restrict__ Bbase, long sB, int ldb,
                void* __restrict__ Cv, int K)
{
    if ((int)blockIdx.x >= *ntiles) return;
    Desc d = desc[blockIdx.x];
    const __half* Bp = Bbase + (long)d.e * sB;
    constexpr int WM = 4 / WN;
    constexpr int BM = WM * FM * 16, BN = WN * FN * 16;
    constexpr int AIT = BM / 64, BIT = BN / 64;
    constexpr int PITCH = 40;
    __shared__ __half As[BM * PITCH];
    __shared__ __half Bs[BN * PITCH];
    const int tid = threadIdx.x, lane = tid & 63, w = tid >> 6;
    const int l15 = lane & 15, g = lane >> 4;
    const int wm = w / WN, wn = w % WN;
    const int n0 = blockIdx.y * (MODE == 0 ? BN / 2 : BN);   // logical j0 / col0

    // staging addresses (constant across k-steps); gather resolved ONCE
    const __half* pA[AIT]; bool aval[AIT]; int adst[AIT];
    const __half* pB[BIT]; int bdst[BIT];
#pragma unroll
    for (int it = 0; it < AIT; ++it) {
        int c = it * 256 + tid, row = c >> 2, kg = c & 3;
        adst[it] = row * PITCH + kg * 8;
        if constexpr (GATHER) {
            aval[it] = row < d.rows;
            int ar = aval[it] ? rowidx[d.base + row] : 0;
            pA[it] = A + (long)ar * lda + kg * 8;
        } else {
            aval[it] = true;
            pA[it] = A + (long)(d.base + row) * lda + kg * 8;
        }
    }
#pragma unroll
    for (int it = 0; it < BIT; ++it) {
        int c = it * 256 + tid, row = c >> 2, kg = c & 3;
        bdst[it] = row * PITCH + kg * 8;
        int srcrow;
        if constexpr (MODE == 0) {
            int pb = row >> 4, w4 = row & 15;
            srcrow = ((pb & 1) ? 2048 : 0) + n0 + (pb >> 1) * 16 + w4;
        } else {
            srcrow = n0 + row;
        }
        pB[it] = Bp + (long)srcrow * ldb + kg * 8;
    }

    uint4 rA[AIT], rB[BIT];
#pragma unroll
    for (int it = 0; it < AIT; ++it)
        rA[it] = aval[it] ? *(const uint4*)(pA[it]) : make_uint4(0, 0, 0, 0);
#pragma unroll
    for (int it = 0; it < BIT; ++it)
        rB[it] = *(const uint4*)(pB[it]);

    f32x4 acc[FM][FN] = {};
    for (int k0 = 0; k0 < K; k0 += 32) {
        BARRIER();                              // prior frag reads consumed
#pragma unroll
        for (int it = 0; it < AIT; ++it) *(uint4*)&As[adst[it]] = rA[it];
#pragma unroll
        for (int it = 0; it < BIT; ++it) *(uint4*)&Bs[bdst[it]] = rB[it];
        if (k0 + 32 < K) {                      // prefetch flies during MFMA
#pragma unroll
            for (int it = 0; it < AIT; ++it)
                rA[it] = aval[it] ? *(const uint4*)(pA[it] + k0 + 32) : make_uint4(0, 0, 0, 0);
#pragma unroll
            for (int it = 0; it < BIT; ++it)
                rB[it] = *(const uint4*)(pB[it] + k0 + 32);
        }
        WAIT_LGKM0();                           // ds_writes visible (no vmcnt drain)
        BARRIER();

        half8 a[FM];
#pragma unroll
        for (int i = 0; i < FM; ++i)
            a[i] = *(const half8*)&As[(wm * FM * 16 + i * 16 + l15) * PITCH + g * 8];
#pragma unroll
        for (int n = 0; n < FN; ++n) {
            half8 b = *(const half8*)&Bs[(wn * FN * 16 + n * 16 + l15) * PITCH + g * 8];
#pragma unroll
            for (int i = 0; i < FM; ++i)
                acc[i][n] = __builtin_amdgcn_mfma_f32_16x16x32_f16(a[i], b, acc[i][n], 0, 0, 0);
        }
    }

    if constexpr (MODE == 0) {
#pragma unroll
        for (int i = 0; i < FM; ++i)
#pragma unroll
        for (int p = 0; p < FN / 2; ++p)
#pragma unroll
        for (int j = 0; j < 4; ++j) {
            int rl = wm * FM * 16 + i * 16 + g * 4 + j;
            float h1 = acc[i][2 * p][j], h2 = acc[i][2 * p + 1][j];
            float a = h1 / (1.0f + expf(-h1)) * h2;
            if (rl >= d.rows) a = 0.0f;
            int jc = n0 + wn * (FN * 8) + p * 16 + l15;
            ((__half*)Cv)[(long)(d.base + rl) * 2048 + jc] = __float2half(a);
        }
    } else {
#pragma unroll
        for (int i = 0; i < FM; ++i)
#pragma unroll
        for (int n = 0; n < FN; ++n)
#pragma unroll
        for (int j = 0; j < 4; ++j) {
            int rl = wm * FM * 16 + i * 16 + g * 4 + j;
            int gn = n0 + wn * FN * 16 + n * 16 + l15;
            ((float*)Cv)[(long)(d.base + rl) * 1024 + gn] = acc[i][n][j];
        }
    }
}

// ---------- transpose fp32 [R][C] -> [C][R], split-fp16 planes out ----------
__global__ __launch_bounds__(256) void k_transpose_pk(const float* __restrict__ src,
    __half* __restrict__ dsth, __half* __restrict__ dstl, int R, int C)
{
    __shared__ float t[64][65];
    const int tid = threadIdx.x;
    const int c0 = blockIdx.x * 64, r0 = blockIdx.y * 64;
#pragma unroll
    for (int it = 0; it < 4; ++it) {
        int idx = it * 256 + tid;
        int r = idx >> 4, c4 = (idx & 15) * 4;
        float4 v = *(const float4*)(src + (long)(r0 + r) * C + c0 + c4);
        t[r][c4] = v.x; t[r][c4 + 1] = v.y; t[r][c4 + 2] = v.z; t[r][c4 + 3] = v.w;
    }
    __syncthreads();
#pragma unroll
    for (int it = 0; it < 4; ++it) {
        int idx = it * 256 + tid;
        int orow = idx >> 4, oc = (idx & 15) * 4;
        __half hs[4], ls[4];
#pragma unroll
        for (int m = 0; m < 4; ++m) split2(t[oc + m][orow], hs[m], ls[m]);
        long o = (long)(c0 + orow) * R + r0 + oc;
        *(uint2*)&dsth[o] = *(uint2*)hs;
        *(uint2*)&dstl[o] = *(uint2*)ls;
    }
}

// ---------- LayerNorm (D=1024, one block per row) ----------
template<int MODE> // 0: hi/lo plane out; 1: f32 + plain fp16 out
__global__ __launch_bounds__(256) void k_ln(const float* __restrict__ X,
    const float* __restrict__ g, const float* __restrict__ bta,
    void* __restrict__ o1, void* __restrict__ o2)
{
    __shared__ float red[4];
    const long row = blockIdx.x;
    const float* xr = X + row * 1024;
    const int c = threadIdx.x * 4;
    float4 v = *(const float4*)(xr + c);
    float mu = blockReduceSum(v.x + v.y + v.z + v.w, red) * (1.0f / 1024.0f);
    float d0 = v.x - mu, d1 = v.y - mu, d2 = v.z - mu, d3 = v.w - mu;
    float var = blockReduceSum(d0 * d0 + d1 * d1 + d2 * d2 + d3 * d3, red) * (1.0f / 1024.0f);
    float rs = 1.0f / sqrtf(var + 1e-5f);
    float4 gv = *(const float4*)(g + c);
    float4 bv = *(const float4*)(bta + c);
    float y[4] = {d0 * rs * gv.x + bv.x, d1 * rs * gv.y + bv.y,
                  d2 * rs * gv.z + bv.z, d3 * rs * gv.w + bv.w};
    if constexpr (MODE == 0) {
        __half hs[4], ls[4];
#pragma unroll
        for (int m = 0; m < 4; ++m) split2(y[m], hs[m], ls[m]);
        *(uint2*)((__half*)o1 + row * 1024 + c) = *(uint2*)hs;
        *(uint2*)((__half*)o2 + row * 1024 + c) = *(uint2*)ls;
    } else {
        *(float4*)((float*)o1 + row * 1024 + c) = make_float4(y[0], y[1], y[2], y[3]);
        __half hs[4];
#pragma unroll
        for (int m = 0; m < 4; ++m) hs[m] = __float2half(y[m]);
        *(uint2*)((__half*)o2 + row * 1024 + c) = *(uint2*)hs;
    }
}

// ---------- RoPE cos/sin table ----------
__global__ __launch_bounds__(256) void k_rope_table(float* __restrict__ ct, float* __restrict__ st)
{
    int idx = blockIdx.x * 256 + threadIdx.x; // 32768 = 1024 t x 32 i
    int t = idx >> 5, i = idx & 31;
    float inv = 1.0f / (float)pow(10000.0, (double)i / 32.0);
    float ang = (float)t * inv;
    ct[idx] = cosf(ang);
    st[idx] = sinf(ang);
}

// ---------- gating: fp32 scores, top-2, no global atomics ----------
__global__ __launch_bounds__(256) void k_gate(const float* __restrict__ xn2,
    const float* __restrict__ gw, const float* __restrict__ eb,
    int* __restrict__ topidx, float* __restrict__ gates,
    float* __restrict__ pprob)
{
    __shared__ float pp[4][8];
    const int lane = threadIdx.x & 63, w = threadIdx.x >> 6;
    const int t = blockIdx.x * 4 + w;
    const float* xr = xn2 + (long)t * 1024;
    float sc[8] = {0, 0, 0, 0, 0, 0, 0, 0};
#pragma unroll
    for (int i = 0; i < 4; ++i) {
        int d = i * 256 + lane * 4;
        float4 xv = *(const float4*)(xr + d);
        float xa[4] = {xv.x, xv.y, xv.z, xv.w};
#pragma unroll
        for (int j = 0; j < 4; ++j) {
            float xx = xa[j];
            const float4* gp = (const float4*)(gw + (long)(d + j) * 8);
            float4 g0 = gp[0], g1 = gp[1];
            sc[0] += xx * g0.x; sc[1] += xx * g0.y; sc[2] += xx * g0.z; sc[3] += xx * g0.w;
            sc[4] += xx * g1.x; sc[5] += xx * g1.y; sc[6] += xx * g1.z; sc[7] += xx * g1.w;
        }
    }
#pragma unroll
    for (int e = 0; e < 8; ++e) {
#pragma unroll
        for (int m = 32; m; m >>= 1) sc[e] += __shfl_xor(sc[e], m);
        sc[e] += eb[e];
    }
    if (lane == 0) {
        int i1 = 0; float v1 = sc[0];
        for (int e = 1; e < 8; ++e) if (sc[e] > v1) { v1 = sc[e]; i1 = e; }
        int i2 = (i1 == 0) ? 1 : 0; float v2 = sc[i2];
        for (int e = 0; e < 8; ++e) if (e != i1 && sc[e] > v2) { v2 = sc[e]; i2 = e; }
        float e2 = expf(v2 - v1);
        gates[t * 2] = 1.0f / (1.0f + e2);
        gates[t * 2 + 1] = e2 / (1.0f + e2);
        topidx[t * 2] = i1; topidx[t * 2 + 1] = i2;
        float mxx = sc[0];
        for (int e = 1; e < 8; ++e) mxx = fmaxf(mxx, sc[e]);
        float se = 0.0f, pe[8];
        for (int e = 0; e < 8; ++e) { pe[e] = expf(sc[e] - mxx); se += pe[e]; }
        float inv = 1.0f / se;
        for (int e = 0; e < 8; ++e) pp[w][e] = pe[e] * inv;
    }
    __syncthreads();
    if (threadIdx.x < 8)
        pprob[(long)blockIdx.x * 8 + threadIdx.x] =
            pp[0][threadIdx.x] + pp[1][threadIdx.x] + pp[2][threadIdx.x] + pp[3][threadIdx.x];
}

// ---------- routing: desc[] round-robin over experts (XCD affinity) ----------
__global__ __launch_bounds__(256) void k_route(const int* __restrict__ topidx,
    int* __restrict__ rowidx, int* __restrict__ invpos,
    int* __restrict__ ntiles, Desc* __restrict__ desc, int* __restrict__ cnt)
{
    __shared__ int cnt_s[8], base_s[8], fill[8];
    const int tid = threadIdx.x;
    if (tid < 8) { cnt_s[tid] = 0; fill[tid] = 0; }
    __syncthreads();
    for (int i = tid; i < 4096; i += 256)
        atomicAdd(&cnt_s[topidx[i]], 1);
    __syncthreads();
    if (tid == 0) {
        int tl[8]; int running = 0, maxT = 0;
        for (int e = 0; e < 8; ++e) {
            int ce = cnt_s[e];
            cnt[e] = ce;
            base_s[e] = running;
            tl[e] = (ce + 127) >> 7;
            running += tl[e] * 128;
            if (tl[e] > maxT) maxT = tl[e];
        }
        int nt = 0;
        for (int r = 0; r < maxT; ++r)
            for (int e = 0; e < 8; ++e)
                if (r < tl[e]) {
                    desc[nt].e = e;
                    desc[nt].base = base_s[e] + r * 128;
                    desc[nt].rows = min(128, cnt_s[e] - r * 128);
                    ++nt;
                }
        *ntiles = nt;
    }
    __syncthreads();
    for (int t = tid; t < 2048; t += 256) {
#pragma unroll
        for (int s = 0; s < 2; ++s) {
            int e = topidx[t * 2 + s];
            int p = base_s[e] + atomicAdd(&fill[e], 1);
            rowidx[p] = t;
            invpos[t * 2 + s] = p;
        }
    }
}

// ---------- combine ----------
__global__ __launch_bounds__(256) void k_combine(const float* __restrict__ x1,
    const float* __restrict__ eo, const int* __restrict__ invpos,
    const float* __restrict__ gates, float* __restrict__ out)
{
    const int t = blockIdx.x, c = threadIdx.x * 4;
    float g0 = gates[t * 2], g1 = gates[t * 2 + 1];
    int p0 = invpos[t * 2], p1 = invpos[t * 2 + 1];
    float4 xv = *(const float4*)(x1 + (long)t * 1024 + c);
    float4 e0 = *(const float4*)(eo + (long)p0 * 1024 + c);
    float4 e1 = *(const float4*)(eo + (long)p1 * 1024 + c);
    float4 o;
    o.x = xv.x + g0 * e0.x + g1 * e1.x;
    o.y = xv.y + g0 * e0.y + g1 * e1.y;
    o.z = xv.z + g0 * e0.z + g1 * e1.z;
    o.w = xv.w + g0 * e0.w + g1 * e1.w;
    *(float4*)(out + (long)t * 1024 + c) = o;
}

// ---------- loss ----------
__global__ __launch_bounds__(256) void k_loss(const int* __restrict__ cnt,
    const float* __restrict__ pprob, float* __restrict__ out)
{
    __shared__ float m[32][8];
    const int tid = threadIdx.x;
    const int e = tid & 7, g = tid >> 3;
    float local = 0.0f;
    for (int b = g; b < 512; b += 32) local += pprob[b * 8 + e];
    m[g][e] = local;
    __syncthreads();
    if (tid == 0) {
        float us = 0, ps = 0, pe[8], ue[8];
        for (int ee = 0; ee < 8; ++ee) {
            float s = 0;
            for (int gg = 0; gg < 32; ++gg) s += m[gg][ee];
            pe[ee] = s; ps += s;
            ue[ee] = (float)cnt[ee]; us += ue[ee];
        }
        float lb = 0;
        for (int ee = 0; ee < 8; ++ee) lb += (ue[ee] / us) * (pe[ee] / ps);
        out[2097152] = lb * 8.0f;
    }
}

// =====================  launch  =====================
extern "C" void kernel_launch(void* const* d_in, const int* in_sizes, int n_in,
                              void* d_out, int out_size, void* d_ws, size_t ws_size,
                              hipStream_t stream)
{
    const float* x    = (const float*)d_in[0];
    const float* ln1g = (const float*)d_in[1];
    const float* ln1b = (const float*)d_in[2];
    const float* qkvw = (const float*)d_in[3];
    const float* outw = (const float*)d_in[4];
    const float* ln2g = (const float*)d_in[5];
    const float* ln2b = (const float*)d_in[6];
    const float* gw   = (const float*)d_in[7];
    const float* eb   = (const float*)d_in[8];
    const float* w1   = (const float*)d_in[9];
    const float* w2   = (const float*)d_in[10];
    float* out = (float*)d_out;
    char* ws = (char*)d_ws;

    // workspace map (bytes), total ~222 MB
    constexpr size_t OFF_QWTH = 0;          // half [3072][1024]
    constexpr size_t OFF_QWTL = 6291456;
    constexpr size_t OFF_OWTH = 12582912;   // half [1024][1024]
    constexpr size_t OFF_OWTL = 14680064;
    constexpr size_t OFF_XN1H = 16777216;   // half [2048][1024]
    constexpr size_t OFF_XN1L = 20971520;
    constexpr size_t OFF_QH   = 25165824;   // half [32][1024][64]
    constexpr size_t OFF_QL   = 29360128;
    constexpr size_t OFF_KH   = 33554432;
    constexpr size_t OFF_KL   = 37748736;
    constexpr size_t OFF_VTH  = 41943040;   // half [32][64][1024]
    constexpr size_t OFF_VTL  = 46137344;
    constexpr size_t OFF_OH   = 50331648;   // half [2048][1024]
    constexpr size_t OFF_OL   = 54525952;
    constexpr size_t OFF_X1   = 58720256;   // f32 [2048][1024]
    constexpr size_t OFF_XN2F = 67108864;   // f32
    constexpr size_t OFF_XN2H = 75497472;   // half
    constexpr size_t OFF_RC   = 79691776;   // f32 [1024][32]
    constexpr size_t OFF_RS   = 79822848;
    constexpr size_t OFF_IDX  = 79953920;   // int [2048][2]
    constexpr size_t OFF_GATES= 79970304;   // f32 [2048][2]
    constexpr size_t OFF_INVP = 79986688;   // int [2048][2]
    constexpr size_t OFF_ROWI = 80003072;   // int [5120]
    constexpr size_t OFF_CNT  = 80023552;   // int [8]
    constexpr size_t OFF_NT   = 80023616;   // int
    constexpr size_t OFF_DESC = 80023680;   // Desc [40]
    constexpr size_t OFF_PPROB= 80024704;   // f32 [512][8]
    constexpr size_t OFF_ACT  = 80041984;   // half [5120][2048]
    constexpr size_t OFF_EO   = 101013504;  // f32 [5120][1024]
    constexpr size_t OFF_W1T  = 121985024;  // half [8][4096][1024]
    constexpr size_t OFF_W2T  = 189093888;  // half [8][1024][2048]

    __half* qwth = (__half*)(ws + OFF_QWTH);
    __half* qwtl = (__half*)(ws + OFF_QWTL);
    __half* owth = (__half*)(ws + OFF_OWTH);
    __half* owtl = (__half*)(ws + OFF_OWTL);
    __half* xn1h = (__half*)(ws + OFF_XN1H);
    __half* xn1l = (__half*)(ws + OFF_XN1L);
    __half* qh   = (__half*)(ws + OFF_QH);
    __half* ql   = (__half*)(ws + OFF_QL);
    __half* kh   = (__half*)(ws + OFF_KH);
    __half* kl   = (__half*)(ws + OFF_KL);
    __half* vth  = (__half*)(ws + OFF_VTH);
    __half* vtl  = (__half*)(ws + OFF_VTL);
    __half* oh   = (__half*)(ws + OFF_OH);
    __half* ol   = (__half*)(ws + OFF_OL);
    float* x1    = (float*)(ws + OFF_X1);
    float* xn2f  = (float*)(ws + OFF_XN2F);
    __half* xn2h = (__half*)(ws + OFF_XN2H);
    float* rc    = (float*)(ws + OFF_RC);
    float* rs    = (float*)(ws + OFF_RS);
    int*   idx   = (int*)(ws + OFF_IDX);
    float* gates = (float*)(ws + OFF_GATES);
    int*   invp  = (int*)(ws + OFF_INVP);
    int*   rowi  = (int*)(ws + OFF_ROWI);
    int*   cnt   = (int*)(ws + OFF_CNT);
    int*   nt    = (int*)(ws + OFF_NT);
    Desc*  desc  = (Desc*)(ws + OFF_DESC);
    float* pprob = (float*)(ws + OFF_PPROB);
    __half* act  = (__half*)(ws + OFF_ACT);
    float* eo    = (float*)(ws + OFF_EO);
    __half* w1t  = (__half*)(ws + OFF_W1T);
    __half* w2t  = (__half*)(ws + OFF_W2T);

    // weight transposes -> split planes (attention) / plain fp16 (MoE)
    k_transpose_pk<<<dim3(48, 16, 1), 256, 0, stream>>>(qkvw, qwth, qwtl, 1024, 3072);
    k_transpose_pk<<<dim3(16, 16, 1), 256, 0, stream>>>(outw, owth, owtl, 1024, 1024);
    k_wconv<<<dim3(64, 16, 8), 256, 0, stream>>>(w1, w1t, 1024, 4096);
    k_wconv<<<dim3(16, 32, 8), 256, 0, stream>>>(w2, w2t, 2048, 1024);
    k_rope_table<<<dim3(128), 256, 0, stream>>>(rc, rs);

    // LN1 -> xn1 planes
    k_ln<0><<<dim3(2048), 256, 0, stream>>>(x, ln1g, ln1b, xn1h, xn1l);

    // QKV GEMM with fused RoPE + q/k/v scatter (64x128 tiles, 768 blocks)
    k_gemm_pk<2, 2, 2, 4, EPI_QKV><<<dim3(32, 24, 1), 256, 0, stream>>>(
        xn1h, xn1l, 1024, qwth, qwtl, 1024, nullptr, 0, 2048, 3072, 1024,
        nullptr, qh, ql, kh, kl, vth, vtl, rc, rs);

    // flash attention -> o planes
    k_flash<<<dim3(16, 32, 1), 256, 0, stream>>>(qh, ql, kh, kl, vth, vtl, oh, ol);

    // x1 = x + o @ out_w
    k_gemm_pk<2, 2, 2, 2, EPI_RESID><<<dim3(32, 16, 1), 256, 0, stream>>>(
        oh, ol, 1024, owth, owtl, 1024, x1, 1024, 2048, 1024, 1024,
        x, nullptr, nullptr, nullptr, nullptr, nullptr, nullptr, nullptr, nullptr);

    // LN2 -> xn2 (f32 for gating, fp16 for MoE)
    k_ln<1><<<dim3(2048), 256, 0, stream>>>(x1, ln2g, ln2b, xn2f, xn2h);

    // gating + routing
    k_gate<<<dim3(512), 256, 0, stream>>>(xn2f, gw, eb, idx, gates, pprob);
    k_route<<<dim3(1), 256, 0, stream>>>(idx, rowi, invp, nt, desc, cnt);

    // MoE GEMM1: act = silu(h1)*h2, 128x128 tiles + T14 prefetch
    k_gemm_moe<true, 0, 4, 4, 2><<<dim3(40, 32, 1), 256, 0, stream>>>(
        xn2h, 1024, rowi, desc, nt, w1t, 4194304, 1024, act, 1024);

    // MoE GEMM2: eo = act @ w2[e], 128x64 tiles + T14 prefetch
    k_gemm_moe<false, 1, 2, 4, 1><<<dim3(40, 16, 1), 256, 0, stream>>>(
        act, 2048, nullptr, desc, nt, w2t, 2097152, 2048, eo, 2048);

    // combine + loss
    k_combine<<<dim3(2048), 256, 0, stream>>>(x1, eo, invp, gates, out);
    k_loss<<<dim3(1), 256, 0, stream>>>(cnt, pprob, out);
}

// Round 15
// 383.508 us; speedup vs baseline: 1.1717x; 1.1717x over previous
//
#include <hip/hip_runtime.h>
#include <hip/hip_fp16.h>

// UnifiedTransformerBlock on MI355X.
// R15: register-prefetch abandoned (R7+R14 both spilled: WRITE_SIZE 18->115MB).
// MoE GEMMs rebuilt as the m97 structure: __builtin_amdgcn_global_load_lds
// (16B/lane DMA, zero VGPR staging) + unpadded LDS + both-sides XOR swizzle
// (source column (c&3)^((c>>3)&3) on DMA, slot g^((l15>>1)&3) on read) ->
// conflict-free fragment reads.  Gather pad rows read a zeroed page (xn1
// region, dead post-QKV).  launch_bounds(256,4) for 4 blocks/CU.
// k_gemm_pk (QKV/resid) and flash unchanged (R6 form).

typedef _Float16 half8 __attribute__((ext_vector_type(8)));
typedef float f32x4 __attribute__((ext_vector_type(4)));

#define DI __device__ __forceinline__

struct Desc { int e, base, rows; };

DI float blockReduceSum(float v, float* red) {
#pragma unroll
    for (int m = 32; m; m >>= 1) v += __shfl_xor(v, m);
    int w = threadIdx.x >> 6;
    if ((threadIdx.x & 63) == 0) red[w] = v;
    __syncthreads();
    v = red[0] + red[1] + red[2] + red[3];
    __syncthreads();
    return v;
}

DI void split2(float v, __half& hi, __half& lo) {
    hi = __float2half(v);
    lo = __float2half((v - __half2float(hi)) * 2048.0f);
}

// ---------- split-fp16 plane GEMM: C = A(MxK) * B^T(NxK) ----------
enum { EPI_RESID = 0, EPI_QKV = 1 };

template<int WM, int WN, int FM, int FN, int EPI>
__global__ __launch_bounds__(256, 2)
void k_gemm_pk(const __half* __restrict__ Ah, const __half* __restrict__ Al, int lda,
               const __half* __restrict__ Bh, const __half* __restrict__ Bl, int ldb,
               float* __restrict__ Cf, int ldc, int M, int N, int K,
               const float* __restrict__ resid,
               __half* __restrict__ qh_p, __half* __restrict__ ql_p,
               __half* __restrict__ kh_p, __half* __restrict__ kl_p,
               __half* __restrict__ vth_p, __half* __restrict__ vtl_p,
               const float* __restrict__ rc, const float* __restrict__ rs)
{
    constexpr int BM = WM * FM * 16, BN = WN * FN * 16;
    constexpr int PITCH = 40;                  // halves: 32 + 8 pad
    __shared__ __half AsH[BM * PITCH], AsL[BM * PITCH];
    __shared__ __half BsH[BN * PITCH], BsL[BN * PITCH];
    const int tid = threadIdx.x;
    const int lane = tid & 63, w = tid >> 6;
    const int l15 = lane & 15, g = lane >> 4;
    const int wm = w / WN, wn = w % WN;
    const int m0 = blockIdx.x * BM, n0 = blockIdx.y * BN;

    f32x4 acc0[FM][FN] = {}; f32x4 acc1[FM][FN] = {};

    for (int k0 = 0; k0 < K; k0 += 32) {
        __syncthreads();
#pragma unroll
        for (int it = 0; it < BM / 64; ++it) {
            int c = it * 256 + tid, row = c >> 2, kg = c & 3;
            long src = (long)(m0 + row) * lda + k0 + kg * 8;
            *(uint4*)&AsH[row * PITCH + kg * 8] = *(const uint4*)(Ah + src);
            *(uint4*)&AsL[row * PITCH + kg * 8] = *(const uint4*)(Al + src);
        }
#pragma unroll
        for (int it = 0; it < BN / 64; ++it) {
            int c = it * 256 + tid, row = c >> 2, kg = c & 3;
            long src = (long)(n0 + row) * ldb + k0 + kg * 8;
            *(uint4*)&BsH[row * PITCH + kg * 8] = *(const uint4*)(Bh + src);
            *(uint4*)&BsL[row * PITCH + kg * 8] = *(const uint4*)(Bl + src);
        }
        __syncthreads();
        half8 ah[FM], al[FM];
#pragma unroll
        for (int i = 0; i < FM; ++i) {
            int ar = (wm * FM * 16 + i * 16 + l15) * PITCH + g * 8;
            ah[i] = *(const half8*)&AsH[ar];
            al[i] = *(const half8*)&AsL[ar];
        }
#pragma unroll
        for (int n = 0; n < FN; ++n) {
            int br = (wn * FN * 16 + n * 16 + l15) * PITCH + g * 8;
            half8 bh = *(const half8*)&BsH[br];
            half8 bl = *(const half8*)&BsL[br];
#pragma unroll
            for (int i = 0; i < FM; ++i) {
                acc0[i][n] = __builtin_amdgcn_mfma_f32_16x16x32_f16(ah[i], bh, acc0[i][n], 0, 0, 0);
                acc1[i][n] = __builtin_amdgcn_mfma_f32_16x16x32_f16(ah[i], bl, acc1[i][n], 0, 0, 0);
                acc1[i][n] = __builtin_amdgcn_mfma_f32_16x16x32_f16(al[i], bh, acc1[i][n], 0, 0, 0);
            }
        }
    }

#pragma unroll
    for (int i = 0; i < FM; ++i)
#pragma unroll
    for (int n = 0; n < FN; ++n)
#pragma unroll
    for (int j = 0; j < 4; ++j) {
        float v = acc0[i][n][j] + acc1[i][n][j] * (1.0f / 2048.0f);
        int gm = m0 + wm * FM * 16 + i * 16 + g * 4 + j;
        int gn = n0 + wn * FN * 16 + n * 16 + l15;
        if constexpr (EPI == EPI_RESID) {
            Cf[(long)gm * ldc + gn] = v + resid[(long)gm * ldc + gn];
        } else {
            // QKV epilogue: RoPE for q/k, transpose-scatter for v, split planes.
            int t = gm & 1023, b = gm >> 10;
            float vp = __shfl_xor(v, 1);       // pair column (uniform control flow)
            if (gn < 2048) {
                int col = gn & 1023;
                int i2 = (col & 63) >> 1;
                float cv = rc[t * 32 + i2], sv = rs[t * 32 + i2];
                float rot = cv * v + sv * ((lane & 1) ? vp : -vp);
                __half hi_, lo_; split2(rot, hi_, lo_);
                long o = ((long)(b * 16 + (col >> 6)) * 1024 + t) * 64 + (col & 63);
                if (gn < 1024) { qh_p[o] = hi_; ql_p[o] = lo_; }
                else           { kh_p[o] = hi_; kl_p[o] = lo_; }
            } else {
                int col = gn - 2048;
                __half hi_, lo_; split2(v, hi_, lo_);
                long o = ((long)(b * 16 + (col >> 6)) * 64 + (col & 63)) * 1024 + t;
                vth_p[o] = hi_; vtl_p[o] = lo_;
            }
        }
    }
}

// ---------- flash attention, split-fp16 planes ----------
__global__ __launch_bounds__(256, 2)
void k_flash(const __half* __restrict__ qh_g, const __half* __restrict__ ql_g,
             const __half* __restrict__ kh_g, const __half* __restrict__ kl_g,
             const __half* __restrict__ vth_g, const __half* __restrict__ vtl_g,
             __half* __restrict__ oh_g, __half* __restrict__ ol_g)
{
    constexpr int P = 72;
    __shared__ __half KsH[64 * P], KsL[64 * P], VsH[64 * P], VsL[64 * P], PsH[64 * P], PsL[64 * P];
    const int tid = threadIdx.x, lane = tid & 63, w = tid >> 6;
    const int l15 = lane & 15, g = lane >> 4;
    const int q0 = blockIdx.x * 64;
    const int bh = blockIdx.y;
    const long base = (long)bh * 65536;

    half8 qhi[2], qlo[2];
    {
        long qoff = base + (long)(q0 + w * 16 + l15) * 64 + g * 8;
        qhi[0] = *(const half8*)(qh_g + qoff); qhi[1] = *(const half8*)(qh_g + qoff + 32);
        qlo[0] = *(const half8*)(ql_g + qoff); qlo[1] = *(const half8*)(ql_g + qoff + 32);
    }

    float m_[4] = {-1e30f, -1e30f, -1e30f, -1e30f};
    float l_[4] = {0.f, 0.f, 0.f, 0.f};
    f32x4 o0[4] = {}, o1[4] = {};

    for (int kt = 0; kt < 16; ++kt) {
        __syncthreads();
#pragma unroll
        for (int it = 0; it < 2; ++it) {
            int c = it * 256 + tid, row = c >> 3, kg = c & 7;
            long src = base + (long)(kt * 64 + row) * 64 + kg * 8;
            *(uint4*)&KsH[row * P + kg * 8] = *(const uint4*)(kh_g + src);
            *(uint4*)&KsL[row * P + kg * 8] = *(const uint4*)(kl_g + src);
            long vs = base + (long)row * 1024 + kt * 64 + kg * 8;
            *(uint4*)&VsH[row * P + kg * 8] = *(const uint4*)(vth_g + vs);
            *(uint4*)&VsL[row * P + kg * 8] = *(const uint4*)(vtl_g + vs);
        }
        __syncthreads();

        f32x4 s0[4] = {}, s1[4] = {};
#pragma unroll
        for (int cf = 0; cf < 4; ++cf) {
            int kr = (cf * 16 + l15) * P + g * 8;
            half8 kh0 = *(const half8*)&KsH[kr], kh1 = *(const half8*)&KsH[kr + 32];
            half8 kl0 = *(const half8*)&KsL[kr], kl1 = *(const half8*)&KsL[kr + 32];
            s0[cf] = __builtin_amdgcn_mfma_f32_16x16x32_f16(qhi[0], kh0, s0[cf], 0, 0, 0);
            s1[cf] = __builtin_amdgcn_mfma_f32_16x16x32_f16(qhi[0], kl0, s1[cf], 0, 0, 0);
            s1[cf] = __builtin_amdgcn_mfma_f32_16x16x32_f16(qlo[0], kh0, s1[cf], 0, 0, 0);
            s0[cf] = __builtin_amdgcn_mfma_f32_16x16x32_f16(qhi[1], kh1, s0[cf], 0, 0, 0);
            s1[cf] = __builtin_amdgcn_mfma_f32_16x16x32_f16(qhi[1], kl1, s1[cf], 0, 0, 0);
            s1[cf] = __builtin_amdgcn_mfma_f32_16x16x32_f16(qlo[1], kh1, s1[cf], 0, 0, 0);
        }

#pragma unroll
        for (int j = 0; j < 4; ++j) {
            float sv[4];
#pragma unroll
            for (int cf = 0; cf < 4; ++cf)
                sv[cf] = (s0[cf][j] + s1[cf][j] * (1.0f / 2048.0f)) * 0.125f;
            float mx = fmaxf(fmaxf(sv[0], sv[1]), fmaxf(sv[2], sv[3]));
#pragma unroll
            for (int msk = 8; msk; msk >>= 1) mx = fmaxf(mx, __shfl_xor(mx, msk));
            float mn = fmaxf(m_[j], mx);
            float r = expf(m_[j] - mn);
            m_[j] = mn;
            float rs = 0.f;
#pragma unroll
            for (int cf = 0; cf < 4; ++cf) {
                float p = expf(sv[cf] - mn);
                rs += p;
                __half hi_, lo_; split2(p, hi_, lo_);
                PsH[(w * 16 + g * 4 + j) * P + cf * 16 + l15] = hi_;
                PsL[(w * 16 + g * 4 + j) * P + cf * 16 + l15] = lo_;
            }
#pragma unroll
            for (int msk = 8; msk; msk >>= 1) rs += __shfl_xor(rs, msk);
            l_[j] = l_[j] * r + rs;
#pragma unroll
            for (int df = 0; df < 4; ++df) { o0[df][j] *= r; o1[df][j] *= r; }
        }
        __syncthreads();

        int pr = (w * 16 + l15) * P + g * 8;
        half8 ph0 = *(const half8*)&PsH[pr], ph1 = *(const half8*)&PsH[pr + 32];
        half8 pl0 = *(const half8*)&PsL[pr], pl1 = *(const half8*)&PsL[pr + 32];
#pragma unroll
        for (int df = 0; df < 4; ++df) {
            int vr = (df * 16 + l15) * P + g * 8;
            half8 vh0 = *(const half8*)&VsH[vr], vh1 = *(const half8*)&VsH[vr + 32];
            half8 vl0 = *(const half8*)&VsL[vr], vl1 = *(const half8*)&VsL[vr + 32];
            o0[df] = __builtin_amdgcn_mfma_f32_16x16x32_f16(ph0, vh0, o0[df], 0, 0, 0);
            o1[df] = __builtin_amdgcn_mfma_f32_16x16x32_f16(ph0, vl0, o1[df], 0, 0, 0);
            o1[df] = __builtin_amdgcn_mfma_f32_16x16x32_f16(pl0, vh0, o1[df], 0, 0, 0);
            o0[df] = __builtin_amdgcn_mfma_f32_16x16x32_f16(ph1, vh1, o0[df], 0, 0, 0);
            o1[df] = __builtin_amdgcn_mfma_f32_16x16x32_f16(ph1, vl1, o1[df], 0, 0, 0);
            o1[df] = __builtin_amdgcn_mfma_f32_16x16x32_f16(pl1, vh1, o1[df], 0, 0, 0);
        }
    }

    float invl[4];
#pragma unroll
    for (int j = 0; j < 4; ++j) invl[j] = 1.0f / l_[j];
    const int b = bh >> 4, hh = bh & 15;
#pragma unroll
    for (int df = 0; df < 4; ++df)
#pragma unroll
    for (int j = 0; j < 4; ++j) {
        float v = (o0[df][j] + o1[df][j] * (1.0f / 2048.0f)) * invl[j];
        long orow = (long)b * 1024 + q0 + w * 16 + g * 4 + j;
        int col = hh * 64 + df * 16 + l15;
        __half hi_, lo_; split2(v, hi_, lo_);
        oh_g[orow * 1024 + col] = hi_;
        ol_g[orow * 1024 + col] = lo_;
    }
}

// ---------- one-time weight convert: fp32 [R][C] -> fp16 [C][R] ----------
__global__ __launch_bounds__(256) void k_wconv(const float* __restrict__ src,
                                               __half* __restrict__ dst, int R, int C)
{
    src += (long)blockIdx.z * R * C;
    dst += (long)blockIdx.z * R * C;
    __shared__ float t[64][65];
    const int tid = threadIdx.x;
    const int c0 = blockIdx.x * 64, r0 = blockIdx.y * 64;
#pragma unroll
    for (int it = 0; it < 4; ++it) {
        int idx = it * 256 + tid;
        int r = idx >> 4, c4 = (idx & 15) * 4;
        float4 v = *(const float4*)(src + (long)(r0 + r) * C + c0 + c4);
        t[r][c4] = v.x; t[r][c4 + 1] = v.y; t[r][c4 + 2] = v.z; t[r][c4 + 3] = v.w;
    }
    __syncthreads();
#pragma unroll
    for (int it = 0; it < 2; ++it) {
        int idx = it * 256 + tid;
        int orow = idx >> 3, oc = (idx & 7) * 8;
        __half v[8];
#pragma unroll
        for (int j = 0; j < 8; ++j) v[j] = __float2half(t[oc + j][orow]);
        *(uint4*)(dst + (long)(c0 + orow) * R + r0 + oc) = *(uint4*)v;
    }
}

// ---------- MoE grouped GEMM: global_load_lds staging (m97 structure) ----------
// LDS layout: unpadded [rows][32] halves; DMA dest is linear (lane c -> byte
// c*16 within 1KB chunk).  Both-sides swizzle: source column granule
// (c&3)^((c>>3)&3); read slot g^((l15>>1)&3)  -> conflict-free ds_read_b128.
// MODE 0: GEMM1 (B rows remapped for h1/h2 pairing, SiLU fused, fp16 out).
// MODE 1: GEMM2 (straight rows, f32 out).
template<bool GATHER, int MODE, int FM, int FN, int WN>
__global__ __launch_bounds__(256, 4)
void k_gemm_moe(const __half* __restrict__ A, int lda, const int* __restrict__ rowidx,
                const Desc* __restrict__ desc, const int* __restrict__ ntiles,
                const __half* __restrict__ Bbase, long sB, int ldb,
                void* __restrict__ Cv, int K, const __half* __restrict__ zp)
{
    if ((int)blockIdx.x >= *ntiles) return;
    Desc d = desc[blockIdx.x];
    const __half* Bp = Bbase + (long)d.e * sB;
    constexpr int WM = 4 / WN;
    constexpr int BM = WM * FM * 16, BN = WN * FN * 16;
    constexpr int ACH = BM / 16, BCH = BN / 16;       // 1KB chunks (16 rows each)
    constexpr int CPW = (ACH + BCH) / 4;              // chunks per wave
    __shared__ __half As[BM * 32];
    __shared__ __half Bs[BN * 32];
    const int tid = threadIdx.x, lane = tid & 63, w = tid >> 6;
    const int l15 = lane & 15, g = lane >> 4;
    const int wm = w / WN, wn = w % WN;
    const int n0 = blockIdx.y * (MODE == 0 ? BN / 2 : BN);

    // per-lane DMA source pointers (k0=0), wave-uniform LDS chunk bases
    const int dlt = lane >> 2;                         // row within chunk
    const int kgs = ((lane & 3) ^ ((lane >> 3) & 3)) * 8;  // swizzled column (halves)
    const __half* src[CPW];
    __half* ldst[CPW];
#pragma unroll
    for (int ci = 0; ci < CPW; ++ci) {
        int chunk = w * CPW + ci;
        if (chunk < ACH) {
            int row = chunk * 16 + dlt;
            ldst[ci] = &As[chunk * 512];
            if constexpr (GATHER) {
                bool valid = row < d.rows;
                int ar = valid ? rowidx[d.base + row] : 0;
                src[ci] = valid ? (A + (long)ar * lda + kgs) : (zp + kgs);
            } else {
                src[ci] = A + (long)(d.base + row) * lda + kgs;
            }
        } else {
            int row = (chunk - ACH) * 16 + dlt;
            int srcrow;
            if constexpr (MODE == 0) {
                int pb = row >> 4, w4 = row & 15;
                srcrow = ((pb & 1) ? 2048 : 0) + n0 + (pb >> 1) * 16 + w4;
            } else {
                srcrow = n0 + row;
            }
            ldst[ci] = &Bs[(chunk - ACH) * 512];
            src[ci] = Bp + (long)srcrow * ldb + kgs;
        }
    }

    const int sg = (g ^ ((l15 >> 1) & 3)) * 8;        // swizzled read slot (halves)

    f32x4 acc[FM][FN] = {};
    for (int k0 = 0; k0 < K; k0 += 32) {
        __syncthreads();                               // prior frag reads done
#pragma unroll
        for (int ci = 0; ci < CPW; ++ci)
            __builtin_amdgcn_global_load_lds((const void*)(src[ci] + k0),
                                             (void*)ldst[ci], 16, 0, 0);
        __syncthreads();                               // vmcnt drain -> LDS ready

        half8 a[FM];
#pragma unroll
        for (int i = 0; i < FM; ++i)
            a[i] = *(const half8*)&As[(wm * FM * 16 + i * 16 + l15) * 32 + sg];
#pragma unroll
        for (int n = 0; n < FN; ++n) {
            half8 b = *(const half8*)&Bs[(wn * FN * 16 + n * 16 + l15) * 32 + sg];
#pragma unroll
            for (int i = 0; i < FM; ++i)
                acc[i][n] = __builtin_amdgcn_mfma_f32_16x16x32_f16(a[i], b, acc[i][n], 0, 0, 0);
        }
    }

    if constexpr (MODE == 0) {
#pragma unroll
        for (int i = 0; i < FM; ++i)
#pragma unroll
        for (int p = 0; p < FN / 2; ++p)
#pragma unroll
        for (int j = 0; j < 4; ++j) {
            int rl = wm * FM * 16 + i * 16 + g * 4 + j;
            float h1 = acc[i][2 * p][j], h2 = acc[i][2 * p + 1][j];
            float a = h1 / (1.0f + expf(-h1)) * h2;
            if (rl >= d.rows) a = 0.0f;
            int jc = n0 + wn * (FN * 8) + p * 16 + l15;
            ((__half*)Cv)[(long)(d.base + rl) * 2048 + jc] = __float2half(a);
        }
    } else {
#pragma unroll
        for (int i = 0; i < FM; ++i)
#pragma unroll
        for (int n = 0; n < FN; ++n)
#pragma unroll
        for (int j = 0; j < 4; ++j) {
            int rl = wm * FM * 16 + i * 16 + g * 4 + j;
            int gn = n0 + wn * FN * 16 + n * 16 + l15;
            ((float*)Cv)[(long)(d.base + rl) * 1024 + gn] = acc[i][n][j];
        }
    }
}

// ---------- transpose fp32 [R][C] -> [C][R], split-fp16 planes out ----------
__global__ __launch_bounds__(256) void k_transpose_pk(const float* __restrict__ src,
    __half* __restrict__ dsth, __half* __restrict__ dstl, int R, int C)
{
    __shared__ float t[64][65];
    const int tid = threadIdx.x;
    const int c0 = blockIdx.x * 64, r0 = blockIdx.y * 64;
#pragma unroll
    for (int it = 0; it < 4; ++it) {
        int idx = it * 256 + tid;
        int r = idx >> 4, c4 = (idx & 15) * 4;
        float4 v = *(const float4*)(src + (long)(r0 + r) * C + c0 + c4);
        t[r][c4] = v.x; t[r][c4 + 1] = v.y; t[r][c4 + 2] = v.z; t[r][c4 + 3] = v.w;
    }
    __syncthreads();
#pragma unroll
    for (int it = 0; it < 4; ++it) {
        int idx = it * 256 + tid;
        int orow = idx >> 4, oc = (idx & 15) * 4;
        __half hs[4], ls[4];
#pragma unroll
        for (int m = 0; m < 4; ++m) split2(t[oc + m][orow], hs[m], ls[m]);
        long o = (long)(c0 + orow) * R + r0 + oc;
        *(uint2*)&dsth[o] = *(uint2*)hs;
        *(uint2*)&dstl[o] = *(uint2*)ls;
    }
}

// ---------- LayerNorm (D=1024, one block per row) ----------
template<int MODE> // 0: hi/lo plane out; 1: f32 + plain fp16 out
__global__ __launch_bounds__(256) void k_ln(const float* __restrict__ X,
    const float* __restrict__ g, const float* __restrict__ bta,
    void* __restrict__ o1, void* __restrict__ o2)
{
    __shared__ float red[4];
    const long row = blockIdx.x;
    const float* xr = X + row * 1024;
    const int c = threadIdx.x * 4;
    float4 v = *(const float4*)(xr + c);
    float mu = blockReduceSum(v.x + v.y + v.z + v.w, red) * (1.0f / 1024.0f);
    float d0 = v.x - mu, d1 = v.y - mu, d2 = v.z - mu, d3 = v.w - mu;
    float var = blockReduceSum(d0 * d0 + d1 * d1 + d2 * d2 + d3 * d3, red) * (1.0f / 1024.0f);
    float rs = 1.0f / sqrtf(var + 1e-5f);
    float4 gv = *(const float4*)(g + c);
    float4 bv = *(const float4*)(bta + c);
    float y[4] = {d0 * rs * gv.x + bv.x, d1 * rs * gv.y + bv.y,
                  d2 * rs * gv.z + bv.z, d3 * rs * gv.w + bv.w};
    if constexpr (MODE == 0) {
        __half hs[4], ls[4];
#pragma unroll
        for (int m = 0; m < 4; ++m) split2(y[m], hs[m], ls[m]);
        *(uint2*)((__half*)o1 + row * 1024 + c) = *(uint2*)hs;
        *(uint2*)((__half*)o2 + row * 1024 + c) = *(uint2*)ls;
    } else {
        *(float4*)((float*)o1 + row * 1024 + c) = make_float4(y[0], y[1], y[2], y[3]);
        __half hs[4];
#pragma unroll
        for (int m = 0; m < 4; ++m) hs[m] = __float2half(y[m]);
        *(uint2*)((__half*)o2 + row * 1024 + c) = *(uint2*)hs;
    }
}

// ---------- RoPE cos/sin table ----------
__global__ __launch_bounds__(256) void k_rope_table(float* __restrict__ ct, float* __restrict__ st)
{
    int idx = blockIdx.x * 256 + threadIdx.x; // 32768 = 1024 t x 32 i
    int t = idx >> 5, i = idx & 31;
    float inv = 1.0f / (float)pow(10000.0, (double)i / 32.0);
    float ang = (float)t * inv;
    ct[idx] = cosf(ang);
    st[idx] = sinf(ang);
}

// ---------- gating: fp32 scores, top-2, no global atomics ----------
__global__ __launch_bounds__(256) void k_gate(const float* __restrict__ xn2,
    const float* __restrict__ gw, const float* __restrict__ eb,
    int* __restrict__ topidx, float* __restrict__ gates,
    float* __restrict__ pprob)
{
    __shared__ float pp[4][8];
    const int lane = threadIdx.x & 63, w = threadIdx.x >> 6;
    const int t = blockIdx.x * 4 + w;
    const float* xr = xn2 + (long)t * 1024;
    float sc[8] = {0, 0, 0, 0, 0, 0, 0, 0};
#pragma unroll
    for (int i = 0; i < 4; ++i) {
        int d = i * 256 + lane * 4;
        float4 xv = *(const float4*)(xr + d);
        float xa[4] = {xv.x, xv.y, xv.z, xv.w};
#pragma unroll
        for (int j = 0; j < 4; ++j) {
            float xx = xa[j];
            const float4* gp = (const float4*)(gw + (long)(d + j) * 8);
            float4 g0 = gp[0], g1 = gp[1];
            sc[0] += xx * g0.x; sc[1] += xx * g0.y; sc[2] += xx * g0.z; sc[3] += xx * g0.w;
            sc[4] += xx * g1.x; sc[5] += xx * g1.y; sc[6] += xx * g1.z; sc[7] += xx * g1.w;
        }
    }
#pragma unroll
    for (int e = 0; e < 8; ++e) {
#pragma unroll
        for (int m = 32; m; m >>= 1) sc[e] += __shfl_xor(sc[e], m);
        sc[e] += eb[e];
    }
    if (lane == 0) {
        int i1 = 0; float v1 = sc[0];
        for (int e = 1; e < 8; ++e) if (sc[e] > v1) { v1 = sc[e]; i1 = e; }
        int i2 = (i1 == 0) ? 1 : 0; float v2 = sc[i2];
        for (int e = 0; e < 8; ++e) if (e != i1 && sc[e] > v2) { v2 = sc[e]; i2 = e; }
        float e2 = expf(v2 - v1);
        gates[t * 2] = 1.0f / (1.0f + e2);
        gates[t * 2 + 1] = e2 / (1.0f + e2);
        topidx[t * 2] = i1; topidx[t * 2 + 1] = i2;
        float mxx = sc[0];
        for (int e = 1; e < 8; ++e) mxx = fmaxf(mxx, sc[e]);
        float se = 0.0f, pe[8];
        for (int e = 0; e < 8; ++e) { pe[e] = expf(sc[e] - mxx); se += pe[e]; }
        float inv = 1.0f / se;
        for (int e = 0; e < 8; ++e) pp[w][e] = pe[e] * inv;
    }
    __syncthreads();
    if (threadIdx.x < 8)
        pprob[(long)blockIdx.x * 8 + threadIdx.x] =
            pp[0][threadIdx.x] + pp[1][threadIdx.x] + pp[2][threadIdx.x] + pp[3][threadIdx.x];
}

// ---------- routing: desc[] round-robin over experts (XCD affinity) ----------
__global__ __launch_bounds__(256) void k_route(const int* __restrict__ topidx,
    int* __restrict__ rowidx, int* __restrict__ invpos,
    int* __restrict__ ntiles, Desc* __restrict__ desc, int* __restrict__ cnt)
{
    __shared__ int cnt_s[8], base_s[8], fill[8];
    const int tid = threadIdx.x;
    if (tid < 8) { cnt_s[tid] = 0; fill[tid] = 0; }
    __syncthreads();
    for (int i = tid; i < 4096; i += 256)
        atomicAdd(&cnt_s[topidx[i]], 1);
    __syncthreads();
    if (tid == 0) {
        int tl[8]; int running = 0, maxT = 0;
        for (int e = 0; e < 8; ++e) {
            int ce = cnt_s[e];
            cnt[e] = ce;
            base_s[e] = running;
            tl[e] = (ce + 127) >> 7;
            running += tl[e] * 128;
            if (tl[e] > maxT) maxT = tl[e];
        }
        int nt = 0;
        for (int r = 0; r < maxT; ++r)
            for (int e = 0; e < 8; ++e)
                if (r < tl[e]) {
                    desc[nt].e = e;
                    desc[nt].base = base_s[e] + r * 128;
                    desc[nt].rows = min(128, cnt_s[e] - r * 128);
                    ++nt;
                }
        *ntiles = nt;
    }
    __syncthreads();
    for (int t = tid; t < 2048; t += 256) {
#pragma unroll
        for (int s = 0; s < 2; ++s) {
            int e = topidx[t * 2 + s];
            int p = base_s[e] + atomicAdd(&fill[e], 1);
            rowidx[p] = t;
            invpos[t * 2 + s] = p;
        }
    }
}

// ---------- combine ----------
__global__ __launch_bounds__(256) void k_combine(const float* __restrict__ x1,
    const float* __restrict__ eo, const int* __restrict__ invpos,
    const float* __restrict__ gates, float* __restrict__ out)
{
    const int t = blockIdx.x, c = threadIdx.x * 4;
    float g0 = gates[t * 2], g1 = gates[t * 2 + 1];
    int p0 = invpos[t * 2], p1 = invpos[t * 2 + 1];
    float4 xv = *(const float4*)(x1 + (long)t * 1024 + c);
    float4 e0 = *(const float4*)(eo + (long)p0 * 1024 + c);
    float4 e1 = *(const float4*)(eo + (long)p1 * 1024 + c);
    float4 o;
    o.x = xv.x + g0 * e0.x + g1 * e1.x;
    o.y = xv.y + g0 * e0.y + g1 * e1.y;
    o.z = xv.z + g0 * e0.z + g1 * e1.z;
    o.w = xv.w + g0 * e0.w + g1 * e1.w;
    *(float4*)(out + (long)t * 1024 + c) = o;
}

// ---------- loss ----------
__global__ __launch_bounds__(256) void k_loss(const int* __restrict__ cnt,
    const float* __restrict__ pprob, float* __restrict__ out)
{
    __shared__ float m[32][8];
    const int tid = threadIdx.x;
    const int e = tid & 7, g = tid >> 3;
    float local = 0.0f;
    for (int b = g; b < 512; b += 32) local += pprob[b * 8 + e];
    m[g][e] = local;
    __syncthreads();
    if (tid == 0) {
        float us = 0, ps = 0, pe[8], ue[8];
        for (int ee = 0; ee < 8; ++ee) {
            float s = 0;
            for (int gg = 0; gg < 32; ++gg) s += m[gg][ee];
            pe[ee] = s; ps += s;
            ue[ee] = (float)cnt[ee]; us += ue[ee];
        }
        float lb = 0;
        for (int ee = 0; ee < 8; ++ee) lb += (ue[ee] / us) * (pe[ee] / ps);
        out[2097152] = lb * 8.0f;
    }
}

// =====================  launch  =====================
extern "C" void kernel_launch(void* const* d_in, const int* in_sizes, int n_in,
                              void* d_out, int out_size, void* d_ws, size_t ws_size,
                              hipStream_t stream)
{
    const float* x    = (const float*)d_in[0];
    const float* ln1g = (const float*)d_in[1];
    const float* ln1b = (const float*)d_in[2];
    const float* qkvw = (const float*)d_in[3];
    const float* outw = (const float*)d_in[4];
    const float* ln2g = (const float*)d_in[5];
    const float* ln2b = (const float*)d_in[6];
    const float* gw   = (const float*)d_in[7];
    const float* eb   = (const float*)d_in[8];
    const float* w1   = (const float*)d_in[9];
    const float* w2   = (const float*)d_in[10];
    float* out = (float*)d_out;
    char* ws = (char*)d_ws;

    // workspace map (bytes), total ~222 MB
    constexpr size_t OFF_QWTH = 0;          // half [3072][1024]
    constexpr size_t OFF_QWTL = 6291456;
    constexpr size_t OFF_OWTH = 12582912;   // half [1024][1024]
    constexpr size_t OFF_OWTL = 14680064;
    constexpr size_t OFF_XN1H = 16777216;   // half [2048][1024]; head doubles as zero page post-QKV
    constexpr size_t OFF_XN1L = 20971520;
    constexpr size_t OFF_QH   = 25165824;   // half [32][1024][64]
    constexpr size_t OFF_QL   = 29360128;
    constexpr size_t OFF_KH   = 33554432;
    constexpr size_t OFF_KL   = 37748736;
    constexpr size_t OFF_VTH  = 41943040;   // half [32][64][1024]
    constexpr size_t OFF_VTL  = 46137344;
    constexpr size_t OFF_OH   = 50331648;   // half [2048][1024]
    constexpr size_t OFF_OL   = 54525952;
    constexpr size_t OFF_X1   = 58720256;   // f32 [2048][1024]
    constexpr size_t OFF_XN2F = 67108864;   // f32
    constexpr size_t OFF_XN2H = 75497472;   // half
    constexpr size_t OFF_RC   = 79691776;   // f32 [1024][32]
    constexpr size_t OFF_RS   = 79822848;
    constexpr size_t OFF_IDX  = 79953920;   // int [2048][2]
    constexpr size_t OFF_GATES= 79970304;   // f32 [2048][2]
    constexpr size_t OFF_INVP = 79986688;   // int [2048][2]
    constexpr size_t OFF_ROWI = 80003072;   // int [5120]
    constexpr size_t OFF_CNT  = 80023552;   // int [8]
    constexpr size_t OFF_NT   = 80023616;   // int
    constexpr size_t OFF_DESC = 80023680;   // Desc [40]
    constexpr size_t OFF_PPROB= 80024704;   // f32 [512][8]
    constexpr size_t OFF_ACT  = 80041984;   // half [5120][2048]
    constexpr size_t OFF_EO   = 101013504;  // f32 [5120][1024]
    constexpr size_t OFF_W1T  = 121985024;  // half [8][4096][1024]
    constexpr size_t OFF_W2T  = 189093888;  // half [8][1024][2048]

    __half* qwth = (__half*)(ws + OFF_QWTH);
    __half* qwtl = (__half*)(ws + OFF_QWTL);
    __half* owth = (__half*)(ws + OFF_OWTH);
    __half* owtl = (__half*)(ws + OFF_OWTL);
    __half* xn1h = (__half*)(ws + OFF_XN1H);
    __half* xn1l = (__half*)(ws + OFF_XN1L);
    __half* qh   = (__half*)(ws + OFF_QH);
    __half* ql   = (__half*)(ws + OFF_QL);
    __half* kh   = (__half*)(ws + OFF_KH);
    __half* kl   = (__half*)(ws + OFF_KL);
    __half* vth  = (__half*)(ws + OFF_VTH);
    __half* vtl  = (__half*)(ws + OFF_VTL);
    __half* oh   = (__half*)(ws + OFF_OH);
    __half* ol   = (__half*)(ws + OFF_OL);
    float* x1    = (float*)(ws + OFF_X1);
    float* xn2f  = (float*)(ws + OFF_XN2F);
    __half* xn2h = (__half*)(ws + OFF_XN2H);
    float* rc    = (float*)(ws + OFF_RC);
    float* rs    = (float*)(ws + OFF_RS);
    int*   idx   = (int*)(ws + OFF_IDX);
    float* gates = (float*)(ws + OFF_GATES);
    int*   invp  = (int*)(ws + OFF_INVP);
    int*   rowi  = (int*)(ws + OFF_ROWI);
    int*   cnt   = (int*)(ws + OFF_CNT);
    int*   nt    = (int*)(ws + OFF_NT);
    Desc*  desc  = (Desc*)(ws + OFF_DESC);
    float* pprob = (float*)(ws + OFF_PPROB);
    __half* act  = (__half*)(ws + OFF_ACT);
    float* eo    = (float*)(ws + OFF_EO);
    __half* w1t  = (__half*)(ws + OFF_W1T);
    __half* w2t  = (__half*)(ws + OFF_W2T);
    __half* zp   = xn1h;                    // zero page (xn1 dead after QKV GEMM)

    // weight transposes -> split planes (attention) / plain fp16 (MoE)
    k_transpose_pk<<<dim3(48, 16, 1), 256, 0, stream>>>(qkvw, qwth, qwtl, 1024, 3072);
    k_transpose_pk<<<dim3(16, 16, 1), 256, 0, stream>>>(outw, owth, owtl, 1024, 1024);
    k_wconv<<<dim3(64, 16, 8), 256, 0, stream>>>(w1, w1t, 1024, 4096);
    k_wconv<<<dim3(16, 32, 8), 256, 0, stream>>>(w2, w2t, 2048, 1024);
    k_rope_table<<<dim3(128), 256, 0, stream>>>(rc, rs);

    // LN1 -> xn1 planes
    k_ln<0><<<dim3(2048), 256, 0, stream>>>(x, ln1g, ln1b, xn1h, xn1l);

    // QKV GEMM with fused RoPE + q/k/v scatter (64x128 tiles, 768 blocks)
    k_gemm_pk<2, 2, 2, 4, EPI_QKV><<<dim3(32, 24, 1), 256, 0, stream>>>(
        xn1h, xn1l, 1024, qwth, qwtl, 1024, nullptr, 0, 2048, 3072, 1024,
        nullptr, qh, ql, kh, kl, vth, vtl, rc, rs);

    // xn1 now dead -> zero its head for the MoE gather pad page
    hipMemsetAsync(zp, 0, 4096, stream);

    // flash attention -> o planes
    k_flash<<<dim3(16, 32, 1), 256, 0, stream>>>(qh, ql, kh, kl, vth, vtl, oh, ol);

    // x1 = x + o @ out_w
    k_gemm_pk<2, 2, 2, 2, EPI_RESID><<<dim3(32, 16, 1), 256, 0, stream>>>(
        oh, ol, 1024, owth, owtl, 1024, x1, 1024, 2048, 1024, 1024,
        x, nullptr, nullptr, nullptr, nullptr, nullptr, nullptr, nullptr, nullptr);

    // LN2 -> xn2 (f32 for gating, fp16 for MoE)
    k_ln<1><<<dim3(2048), 256, 0, stream>>>(x1, ln2g, ln2b, xn2f, xn2h);

    // gating + routing
    k_gate<<<dim3(512), 256, 0, stream>>>(xn2f, gw, eb, idx, gates, pprob);
    k_route<<<dim3(1), 256, 0, stream>>>(idx, rowi, invp, nt, desc, cnt);

    // MoE GEMM1: act = silu(h1)*h2, 128x128 tiles, global_load_lds staging
    k_gemm_moe<true, 0, 4, 4, 2><<<dim3(40, 32, 1), 256, 0, stream>>>(
        xn2h, 1024, rowi, desc, nt, w1t, 4194304, 1024, act, 1024, zp);

    // MoE GEMM2: eo = act @ w2[e], 128x64 tiles, global_load_lds staging
    k_gemm_moe<false, 1, 2, 4, 1><<<dim3(40, 16, 1), 256, 0, stream>>>(
        act, 2048, nullptr, desc, nt, w2t, 2097152, 2048, eo, 2048, zp);

    // combine + loss
    k_combine<<<dim3(2048), 256, 0, stream>>>(x1, eo, invp, gates, out);
    k_loss<<<dim3(1), 256, 0, stream>>>(cnt, pprob, out);
}

// Round 16
// 380.848 us; speedup vs baseline: 1.1799x; 1.0070x over previous
//
#include <hip/hip_runtime.h>
#include <hip/hip_fp16.h>

// UnifiedTransformerBlock on MI355X.
// R16: MoE GEMMs upgraded from single-buffer (R15: stage->drain->compute,
// full DMA latency exposed per k-step) to T3 "minimum 2-phase": LDS double
// buffer, stage(t+1) via global_load_lds issued BEFORE MFMA(t), ONE
// __syncthreads per k-step placed after compute so the drain overlaps.
// Zero VGPR staging (R7/R14 spill trap structurally impossible).
// R15 kept: both-sides XOR swizzle (bank-conflict 0), zero-page gather pad,
// expert->XCD desc ordering, fused SiLU.  k_gemm_pk/flash unchanged.

typedef _Float16 half8 __attribute__((ext_vector_type(8)));
typedef float f32x4 __attribute__((ext_vector_type(4)));

#define DI __device__ __forceinline__

struct Desc { int e, base, rows; };

DI float blockReduceSum(float v, float* red) {
#pragma unroll
    for (int m = 32; m; m >>= 1) v += __shfl_xor(v, m);
    int w = threadIdx.x >> 6;
    if ((threadIdx.x & 63) == 0) red[w] = v;
    __syncthreads();
    v = red[0] + red[1] + red[2] + red[3];
    __syncthreads();
    return v;
}

DI void split2(float v, __half& hi, __half& lo) {
    hi = __float2half(v);
    lo = __float2half((v - __half2float(hi)) * 2048.0f);
}

// ---------- split-fp16 plane GEMM: C = A(MxK) * B^T(NxK) ----------
enum { EPI_RESID = 0, EPI_QKV = 1 };

template<int WM, int WN, int FM, int FN, int EPI>
__global__ __launch_bounds__(256, 2)
void k_gemm_pk(const __half* __restrict__ Ah, const __half* __restrict__ Al, int lda,
               const __half* __restrict__ Bh, const __half* __restrict__ Bl, int ldb,
               float* __restrict__ Cf, int ldc, int M, int N, int K,
               const float* __restrict__ resid,
               __half* __restrict__ qh_p, __half* __restrict__ ql_p,
               __half* __restrict__ kh_p, __half* __restrict__ kl_p,
               __half* __restrict__ vth_p, __half* __restrict__ vtl_p,
               const float* __restrict__ rc, const float* __restrict__ rs)
{
    constexpr int BM = WM * FM * 16, BN = WN * FN * 16;
    constexpr int PITCH = 40;                  // halves: 32 + 8 pad
    __shared__ __half AsH[BM * PITCH], AsL[BM * PITCH];
    __shared__ __half BsH[BN * PITCH], BsL[BN * PITCH];
    const int tid = threadIdx.x;
    const int lane = tid & 63, w = tid >> 6;
    const int l15 = lane & 15, g = lane >> 4;
    const int wm = w / WN, wn = w % WN;
    const int m0 = blockIdx.x * BM, n0 = blockIdx.y * BN;

    f32x4 acc0[FM][FN] = {}; f32x4 acc1[FM][FN] = {};

    for (int k0 = 0; k0 < K; k0 += 32) {
        __syncthreads();
#pragma unroll
        for (int it = 0; it < BM / 64; ++it) {
            int c = it * 256 + tid, row = c >> 2, kg = c & 3;
            long src = (long)(m0 + row) * lda + k0 + kg * 8;
            *(uint4*)&AsH[row * PITCH + kg * 8] = *(const uint4*)(Ah + src);
            *(uint4*)&AsL[row * PITCH + kg * 8] = *(const uint4*)(Al + src);
        }
#pragma unroll
        for (int it = 0; it < BN / 64; ++it) {
            int c = it * 256 + tid, row = c >> 2, kg = c & 3;
            long src = (long)(n0 + row) * ldb + k0 + kg * 8;
            *(uint4*)&BsH[row * PITCH + kg * 8] = *(const uint4*)(Bh + src);
            *(uint4*)&BsL[row * PITCH + kg * 8] = *(const uint4*)(Bl + src);
        }
        __syncthreads();
        half8 ah[FM], al[FM];
#pragma unroll
        for (int i = 0; i < FM; ++i) {
            int ar = (wm * FM * 16 + i * 16 + l15) * PITCH + g * 8;
            ah[i] = *(const half8*)&AsH[ar];
            al[i] = *(const half8*)&AsL[ar];
        }
#pragma unroll
        for (int n = 0; n < FN; ++n) {
            int br = (wn * FN * 16 + n * 16 + l15) * PITCH + g * 8;
            half8 bh = *(const half8*)&BsH[br];
            half8 bl = *(const half8*)&BsL[br];
#pragma unroll
            for (int i = 0; i < FM; ++i) {
                acc0[i][n] = __builtin_amdgcn_mfma_f32_16x16x32_f16(ah[i], bh, acc0[i][n], 0, 0, 0);
                acc1[i][n] = __builtin_amdgcn_mfma_f32_16x16x32_f16(ah[i], bl, acc1[i][n], 0, 0, 0);
                acc1[i][n] = __builtin_amdgcn_mfma_f32_16x16x32_f16(al[i], bh, acc1[i][n], 0, 0, 0);
            }
        }
    }

#pragma unroll
    for (int i = 0; i < FM; ++i)
#pragma unroll
    for (int n = 0; n < FN; ++n)
#pragma unroll
    for (int j = 0; j < 4; ++j) {
        float v = acc0[i][n][j] + acc1[i][n][j] * (1.0f / 2048.0f);
        int gm = m0 + wm * FM * 16 + i * 16 + g * 4 + j;
        int gn = n0 + wn * FN * 16 + n * 16 + l15;
        if constexpr (EPI == EPI_RESID) {
            Cf[(long)gm * ldc + gn] = v + resid[(long)gm * ldc + gn];
        } else {
            // QKV epilogue: RoPE for q/k, transpose-scatter for v, split planes.
            int t = gm & 1023, b = gm >> 10;
            float vp = __shfl_xor(v, 1);       // pair column (uniform control flow)
            if (gn < 2048) {
                int col = gn & 1023;
                int i2 = (col & 63) >> 1;
                float cv = rc[t * 32 + i2], sv = rs[t * 32 + i2];
                float rot = cv * v + sv * ((lane & 1) ? vp : -vp);
                __half hi_, lo_; split2(rot, hi_, lo_);
                long o = ((long)(b * 16 + (col >> 6)) * 1024 + t) * 64 + (col & 63);
                if (gn < 1024) { qh_p[o] = hi_; ql_p[o] = lo_; }
                else           { kh_p[o] = hi_; kl_p[o] = lo_; }
            } else {
                int col = gn - 2048;
                __half hi_, lo_; split2(v, hi_, lo_);
                long o = ((long)(b * 16 + (col >> 6)) * 64 + (col & 63)) * 1024 + t;
                vth_p[o] = hi_; vtl_p[o] = lo_;
            }
        }
    }
}

// ---------- flash attention, split-fp16 planes ----------
__global__ __launch_bounds__(256, 2)
void k_flash(const __half* __restrict__ qh_g, const __half* __restrict__ ql_g,
             const __half* __restrict__ kh_g, const __half* __restrict__ kl_g,
             const __half* __restrict__ vth_g, const __half* __restrict__ vtl_g,
             __half* __restrict__ oh_g, __half* __restrict__ ol_g)
{
    constexpr int P = 72;
    __shared__ __half KsH[64 * P], KsL[64 * P], VsH[64 * P], VsL[64 * P], PsH[64 * P], PsL[64 * P];
    const int tid = threadIdx.x, lane = tid & 63, w = tid >> 6;
    const int l15 = lane & 15, g = lane >> 4;
    const int q0 = blockIdx.x * 64;
    const int bh = blockIdx.y;
    const long base = (long)bh * 65536;

    half8 qhi[2], qlo[2];
    {
        long qoff = base + (long)(q0 + w * 16 + l15) * 64 + g * 8;
        qhi[0] = *(const half8*)(qh_g + qoff); qhi[1] = *(const half8*)(qh_g + qoff + 32);
        qlo[0] = *(const half8*)(ql_g + qoff); qlo[1] = *(const half8*)(ql_g + qoff + 32);
    }

    float m_[4] = {-1e30f, -1e30f, -1e30f, -1e30f};
    float l_[4] = {0.f, 0.f, 0.f, 0.f};
    f32x4 o0[4] = {}, o1[4] = {};

    for (int kt = 0; kt < 16; ++kt) {
        __syncthreads();
#pragma unroll
        for (int it = 0; it < 2; ++it) {
            int c = it * 256 + tid, row = c >> 3, kg = c & 7;
            long src = base + (long)(kt * 64 + row) * 64 + kg * 8;
            *(uint4*)&KsH[row * P + kg * 8] = *(const uint4*)(kh_g + src);
            *(uint4*)&KsL[row * P + kg * 8] = *(const uint4*)(kl_g + src);
            long vs = base + (long)row * 1024 + kt * 64 + kg * 8;
            *(uint4*)&VsH[row * P + kg * 8] = *(const uint4*)(vth_g + vs);
            *(uint4*)&VsL[row * P + kg * 8] = *(const uint4*)(vtl_g + vs);
        }
        __syncthreads();

        f32x4 s0[4] = {}, s1[4] = {};
#pragma unroll
        for (int cf = 0; cf < 4; ++cf) {
            int kr = (cf * 16 + l15) * P + g * 8;
            half8 kh0 = *(const half8*)&KsH[kr], kh1 = *(const half8*)&KsH[kr + 32];
            half8 kl0 = *(const half8*)&KsL[kr], kl1 = *(const half8*)&KsL[kr + 32];
            s0[cf] = __builtin_amdgcn_mfma_f32_16x16x32_f16(qhi[0], kh0, s0[cf], 0, 0, 0);
            s1[cf] = __builtin_amdgcn_mfma_f32_16x16x32_f16(qhi[0], kl0, s1[cf], 0, 0, 0);
            s1[cf] = __builtin_amdgcn_mfma_f32_16x16x32_f16(qlo[0], kh0, s1[cf], 0, 0, 0);
            s0[cf] = __builtin_amdgcn_mfma_f32_16x16x32_f16(qhi[1], kh1, s0[cf], 0, 0, 0);
            s1[cf] = __builtin_amdgcn_mfma_f32_16x16x32_f16(qhi[1], kl1, s1[cf], 0, 0, 0);
            s1[cf] = __builtin_amdgcn_mfma_f32_16x16x32_f16(qlo[1], kh1, s1[cf], 0, 0, 0);
        }

#pragma unroll
        for (int j = 0; j < 4; ++j) {
            float sv[4];
#pragma unroll
            for (int cf = 0; cf < 4; ++cf)
                sv[cf] = (s0[cf][j] + s1[cf][j] * (1.0f / 2048.0f)) * 0.125f;
            float mx = fmaxf(fmaxf(sv[0], sv[1]), fmaxf(sv[2], sv[3]));
#pragma unroll
            for (int msk = 8; msk; msk >>= 1) mx = fmaxf(mx, __shfl_xor(mx, msk));
            float mn = fmaxf(m_[j], mx);
            float r = expf(m_[j] - mn);
            m_[j] = mn;
            float rs = 0.f;
#pragma unroll
            for (int cf = 0; cf < 4; ++cf) {
                float p = expf(sv[cf] - mn);
                rs += p;
                __half hi_, lo_; split2(p, hi_, lo_);
                PsH[(w * 16 + g * 4 + j) * P + cf * 16 + l15] = hi_;
                PsL[(w * 16 + g * 4 + j) * P + cf * 16 + l15] = lo_;
            }
#pragma unroll
            for (int msk = 8; msk; msk >>= 1) rs += __shfl_xor(rs, msk);
            l_[j] = l_[j] * r + rs;
#pragma unroll
            for (int df = 0; df < 4; ++df) { o0[df][j] *= r; o1[df][j] *= r; }
        }
        __syncthreads();

        int pr = (w * 16 + l15) * P + g * 8;
        half8 ph0 = *(const half8*)&PsH[pr], ph1 = *(const half8*)&PsH[pr + 32];
        half8 pl0 = *(const half8*)&PsL[pr], pl1 = *(const half8*)&PsL[pr + 32];
#pragma unroll
        for (int df = 0; df < 4; ++df) {
            int vr = (df * 16 + l15) * P + g * 8;
            half8 vh0 = *(const half8*)&VsH[vr], vh1 = *(const half8*)&VsH[vr + 32];
            half8 vl0 = *(const half8*)&VsL[vr], vl1 = *(const half8*)&VsL[vr + 32];
            o0[df] = __builtin_amdgcn_mfma_f32_16x16x32_f16(ph0, vh0, o0[df], 0, 0, 0);
            o1[df] = __builtin_amdgcn_mfma_f32_16x16x32_f16(ph0, vl0, o1[df], 0, 0, 0);
            o1[df] = __builtin_amdgcn_mfma_f32_16x16x32_f16(pl0, vh0, o1[df], 0, 0, 0);
            o0[df] = __builtin_amdgcn_mfma_f32_16x16x32_f16(ph1, vh1, o0[df], 0, 0, 0);
            o1[df] = __builtin_amdgcn_mfma_f32_16x16x32_f16(ph1, vl1, o1[df], 0, 0, 0);
            o1[df] = __builtin_amdgcn_mfma_f32_16x16x32_f16(pl1, vh1, o1[df], 0, 0, 0);
        }
    }

    float invl[4];
#pragma unroll
    for (int j = 0; j < 4; ++j) invl[j] = 1.0f / l_[j];
    const int b = bh >> 4, hh = bh & 15;
#pragma unroll
    for (int df = 0; df < 4; ++df)
#pragma unroll
    for (int j = 0; j < 4; ++j) {
        float v = (o0[df][j] + o1[df][j] * (1.0f / 2048.0f)) * invl[j];
        long orow = (long)b * 1024 + q0 + w * 16 + g * 4 + j;
        int col = hh * 64 + df * 16 + l15;
        __half hi_, lo_; split2(v, hi_, lo_);
        oh_g[orow * 1024 + col] = hi_;
        ol_g[orow * 1024 + col] = lo_;
    }
}

// ---------- one-time weight convert: fp32 [R][C] -> fp16 [C][R] ----------
__global__ __launch_bounds__(256) void k_wconv(const float* __restrict__ src,
                                               __half* __restrict__ dst, int R, int C)
{
    src += (long)blockIdx.z * R * C;
    dst += (long)blockIdx.z * R * C;
    __shared__ float t[64][65];
    const int tid = threadIdx.x;
    const int c0 = blockIdx.x * 64, r0 = blockIdx.y * 64;
#pragma unroll
    for (int it = 0; it < 4; ++it) {
        int idx = it * 256 + tid;
        int r = idx >> 4, c4 = (idx & 15) * 4;
        float4 v = *(const float4*)(src + (long)(r0 + r) * C + c0 + c4);
        t[r][c4] = v.x; t[r][c4 + 1] = v.y; t[r][c4 + 2] = v.z; t[r][c4 + 3] = v.w;
    }
    __syncthreads();
#pragma unroll
    for (int it = 0; it < 2; ++it) {
        int idx = it * 256 + tid;
        int orow = idx >> 3, oc = (idx & 7) * 8;
        __half v[8];
#pragma unroll
        for (int j = 0; j < 8; ++j) v[j] = __float2half(t[oc + j][orow]);
        *(uint4*)(dst + (long)(c0 + orow) * R + r0 + oc) = *(uint4*)v;
    }
}

// ---------- MoE grouped GEMM: double-buffered global_load_lds (2-phase) ----------
// LDS: S[2][(BM+BN)*32] halves, chunk c -> S[buf][c*512], linear DMA dest.
// Both-sides swizzle: source column granule (c&3)^((c>>3)&3) on DMA; read
// slot g^((l15>>1)&3).  stage(t+1) issued BEFORE MFMA(t); single barrier
// per k-step after compute -> DMA latency hides under MFMA.
// MODE 0: GEMM1 (B rows remapped for h1/h2 pairing, SiLU fused, fp16 out).
// MODE 1: GEMM2 (straight rows, f32 out).
template<bool GATHER, int MODE, int FM, int FN, int WN>
__global__ __launch_bounds__(256, 4)
void k_gemm_moe(const __half* __restrict__ A, int lda, const int* __restrict__ rowidx,
                const Desc* __restrict__ desc, const int* __restrict__ ntiles,
                const __half* __restrict__ Bbase, long sB, int ldb,
                void* __restrict__ Cv, int K, const __half* __restrict__ zp)
{
    if ((int)blockIdx.x >= *ntiles) return;
    Desc d = desc[blockIdx.x];
    const __half* Bp = Bbase + (long)d.e * sB;
    constexpr int WM = 4 / WN;
    constexpr int BM = WM * FM * 16, BN = WN * FN * 16;
    constexpr int ACH = BM / 16, BCH = BN / 16;       // 1KB chunks (16 rows each)
    constexpr int NCH = ACH + BCH;
    constexpr int CPW = NCH / 4;                      // chunks per wave
    constexpr int HALF_PER_BUF = NCH * 512;
    __shared__ __half S[2][HALF_PER_BUF];             // [buf][chunk*512 + ...]
    const int tid = threadIdx.x, lane = tid & 63, w = tid >> 6;
    const int l15 = lane & 15, g = lane >> 4;
    const int wm = w / WN, wn = w % WN;
    const int n0 = blockIdx.y * (MODE == 0 ? BN / 2 : BN);

    // per-lane DMA source pointers (k0=0); LDS chunk offsets (buf-relative)
    const int dlt = lane >> 2;                         // row within chunk
    const int kgs = ((lane & 3) ^ ((lane >> 3) & 3)) * 8;  // swizzled column (halves)
    const __half* src[CPW];
    int loff[CPW];
#pragma unroll
    for (int ci = 0; ci < CPW; ++ci) {
        int chunk = w * CPW + ci;
        loff[ci] = chunk * 512;
        if (chunk < ACH) {
            int row = chunk * 16 + dlt;
            if constexpr (GATHER) {
                bool valid = row < d.rows;
                int ar = valid ? rowidx[d.base + row] : 0;
                src[ci] = valid ? (A + (long)ar * lda + kgs) : (zp + kgs);
            } else {
                src[ci] = A + (long)(d.base + row) * lda + kgs;
            }
        } else {
            int row = (chunk - ACH) * 16 + dlt;
            int srcrow;
            if constexpr (MODE == 0) {
                int pb = row >> 4, w4 = row & 15;
                srcrow = ((pb & 1) ? 2048 : 0) + n0 + (pb >> 1) * 16 + w4;
            } else {
                srcrow = n0 + row;
            }
            src[ci] = Bp + (long)srcrow * ldb + kgs;
        }
    }

    const int sg = (g ^ ((l15 >> 1) & 3)) * 8;        // swizzled read slot (halves)
    const int arow = (wm * FM * 16 + l15) * 32 + sg;
    const int brow = BM * 32 + (wn * FN * 16 + l15) * 32 + sg;

    // prologue: stage k=0 into buf 0, drain
#pragma unroll
    for (int ci = 0; ci < CPW; ++ci)
        __builtin_amdgcn_global_load_lds((const void*)(src[ci]),
                                         (void*)&S[0][loff[ci]], 16, 0, 0);
    __syncthreads();

    f32x4 acc[FM][FN] = {};
    int cur = 0;
    for (int k0 = 0; k0 < K; k0 += 32) {
        if (k0 + 32 < K) {                             // stage next tile (flies during MFMA)
            const __half* sb = &S[cur ^ 1][0];
#pragma unroll
            for (int ci = 0; ci < CPW; ++ci)
                __builtin_amdgcn_global_load_lds((const void*)(src[ci] + k0 + 32),
                                                 (void*)(sb + loff[ci]), 16, 0, 0);
        }
        const __half* sc = &S[cur][0];
        half8 a[FM];
#pragma unroll
        for (int i = 0; i < FM; ++i)
            a[i] = *(const half8*)(sc + arow + i * 512);
#pragma unroll
        for (int n = 0; n < FN; ++n) {
            half8 b = *(const half8*)(sc + brow + n * 512);
#pragma unroll
            for (int i = 0; i < FM; ++i)
                acc[i][n] = __builtin_amdgcn_mfma_f32_16x16x32_f16(a[i], b, acc[i][n], 0, 0, 0);
        }
        __syncthreads();                               // drains next-tile DMA after compute
        cur ^= 1;
    }

    if constexpr (MODE == 0) {
#pragma unroll
        for (int i = 0; i < FM; ++i)
#pragma unroll
        for (int p = 0; p < FN / 2; ++p)
#pragma unroll
        for (int j = 0; j < 4; ++j) {
            int rl = wm * FM * 16 + i * 16 + g * 4 + j;
            float h1 = acc[i][2 * p][j], h2 = acc[i][2 * p + 1][j];
            float a = h1 / (1.0f + expf(-h1)) * h2;
            if (rl >= d.rows) a = 0.0f;
            int jc = n0 + wn * (FN * 8) + p * 16 + l15;
            ((__half*)Cv)[(long)(d.base + rl) * 2048 + jc] = __float2half(a);
        }
    } else {
#pragma unroll
        for (int i = 0; i < FM; ++i)
#pragma unroll
        for (int n = 0; n < FN; ++n)
#pragma unroll
        for (int j = 0; j < 4; ++j) {
            int rl = wm * FM * 16 + i * 16 + g * 4 + j;
            int gn = n0 + wn * FN * 16 + n * 16 + l15;
            ((float*)Cv)[(long)(d.base + rl) * 1024 + gn] = acc[i][n][j];
        }
    }
}

// ---------- transpose fp32 [R][C] -> [C][R], split-fp16 planes out ----------
__global__ __launch_bounds__(256) void k_transpose_pk(const float* __restrict__ src,
    __half* __restrict__ dsth, __half* __restrict__ dstl, int R, int C)
{
    __shared__ float t[64][65];
    const int tid = threadIdx.x;
    const int c0 = blockIdx.x * 64, r0 = blockIdx.y * 64;
#pragma unroll
    for (int it = 0; it < 4; ++it) {
        int idx = it * 256 + tid;
        int r = idx >> 4, c4 = (idx & 15) * 4;
        float4 v = *(const float4*)(src + (long)(r0 + r) * C + c0 + c4);
        t[r][c4] = v.x; t[r][c4 + 1] = v.y; t[r][c4 + 2] = v.z; t[r][c4 + 3] = v.w;
    }
    __syncthreads();
#pragma unroll
    for (int it = 0; it < 4; ++it) {
        int idx = it * 256 + tid;
        int orow = idx >> 4, oc = (idx & 15) * 4;
        __half hs[4], ls[4];
#pragma unroll
        for (int m = 0; m < 4; ++m) split2(t[oc + m][orow], hs[m], ls[m]);
        long o = (long)(c0 + orow) * R + r0 + oc;
        *(uint2*)&dsth[o] = *(uint2*)hs;
        *(uint2*)&dstl[o] = *(uint2*)ls;
    }
}

// ---------- LayerNorm (D=1024, one block per row) ----------
template<int MODE> // 0: hi/lo plane out; 1: f32 + plain fp16 out
__global__ __launch_bounds__(256) void k_ln(const float* __restrict__ X,
    const float* __restrict__ g, const float* __restrict__ bta,
    void* __restrict__ o1, void* __restrict__ o2)
{
    __shared__ float red[4];
    const long row = blockIdx.x;
    const float* xr = X + row * 1024;
    const int c = threadIdx.x * 4;
    float4 v = *(const float4*)(xr + c);
    float mu = blockReduceSum(v.x + v.y + v.z + v.w, red) * (1.0f / 1024.0f);
    float d0 = v.x - mu, d1 = v.y - mu, d2 = v.z - mu, d3 = v.w - mu;
    float var = blockReduceSum(d0 * d0 + d1 * d1 + d2 * d2 + d3 * d3, red) * (1.0f / 1024.0f);
    float rs = 1.0f / sqrtf(var + 1e-5f);
    float4 gv = *(const float4*)(g + c);
    float4 bv = *(const float4*)(bta + c);
    float y[4] = {d0 * rs * gv.x + bv.x, d1 * rs * gv.y + bv.y,
                  d2 * rs * gv.z + bv.z, d3 * rs * gv.w + bv.w};
    if constexpr (MODE == 0) {
        __half hs[4], ls[4];
#pragma unroll
        for (int m = 0; m < 4; ++m) split2(y[m], hs[m], ls[m]);
        *(uint2*)((__half*)o1 + row * 1024 + c) = *(uint2*)hs;
        *(uint2*)((__half*)o2 + row * 1024 + c) = *(uint2*)ls;
    } else {
        *(float4*)((float*)o1 + row * 1024 + c) = make_float4(y[0], y[1], y[2], y[3]);
        __half hs[4];
#pragma unroll
        for (int m = 0; m < 4; ++m) hs[m] = __float2half(y[m]);
        *(uint2*)((__half*)o2 + row * 1024 + c) = *(uint2*)hs;
    }
}

// ---------- RoPE cos/sin table ----------
__global__ __launch_bounds__(256) void k_rope_table(float* __restrict__ ct, float* __restrict__ st)
{
    int idx = blockIdx.x * 256 + threadIdx.x; // 32768 = 1024 t x 32 i
    int t = idx >> 5, i = idx & 31;
    float inv = 1.0f / (float)pow(10000.0, (double)i / 32.0);
    float ang = (float)t * inv;
    ct[idx] = cosf(ang);
    st[idx] = sinf(ang);
}

// ---------- gating: fp32 scores, top-2, no global atomics ----------
__global__ __launch_bounds__(256) void k_gate(const float* __restrict__ xn2,
    const float* __restrict__ gw, const float* __restrict__ eb,
    int* __restrict__ topidx, float* __restrict__ gates,
    float* __restrict__ pprob)
{
    __shared__ float pp[4][8];
    const int lane = threadIdx.x & 63, w = threadIdx.x >> 6;
    const int t = blockIdx.x * 4 + w;
    const float* xr = xn2 + (long)t * 1024;
    float sc[8] = {0, 0, 0, 0, 0, 0, 0, 0};
#pragma unroll
    for (int i = 0; i < 4; ++i) {
        int d = i * 256 + lane * 4;
        float4 xv = *(const float4*)(xr + d);
        float xa[4] = {xv.x, xv.y, xv.z, xv.w};
#pragma unroll
        for (int j = 0; j < 4; ++j) {
            float xx = xa[j];
            const float4* gp = (const float4*)(gw + (long)(d + j) * 8);
            float4 g0 = gp[0], g1 = gp[1];
            sc[0] += xx * g0.x; sc[1] += xx * g0.y; sc[2] += xx * g0.z; sc[3] += xx * g0.w;
            sc[4] += xx * g1.x; sc[5] += xx * g1.y; sc[6] += xx * g1.z; sc[7] += xx * g1.w;
        }
    }
#pragma unroll
    for (int e = 0; e < 8; ++e) {
#pragma unroll
        for (int m = 32; m; m >>= 1) sc[e] += __shfl_xor(sc[e], m);
        sc[e] += eb[e];
    }
    if (lane == 0) {
        int i1 = 0; float v1 = sc[0];
        for (int e = 1; e < 8; ++e) if (sc[e] > v1) { v1 = sc[e]; i1 = e; }
        int i2 = (i1 == 0) ? 1 : 0; float v2 = sc[i2];
        for (int e = 0; e < 8; ++e) if (e != i1 && sc[e] > v2) { v2 = sc[e]; i2 = e; }
        float e2 = expf(v2 - v1);
        gates[t * 2] = 1.0f / (1.0f + e2);
        gates[t * 2 + 1] = e2 / (1.0f + e2);
        topidx[t * 2] = i1; topidx[t * 2 + 1] = i2;
        float mxx = sc[0];
        for (int e = 1; e < 8; ++e) mxx = fmaxf(mxx, sc[e]);
        float se = 0.0f, pe[8];
        for (int e = 0; e < 8; ++e) { pe[e] = expf(sc[e] - mxx); se += pe[e]; }
        float inv = 1.0f / se;
        for (int e = 0; e < 8; ++e) pp[w][e] = pe[e] * inv;
    }
    __syncthreads();
    if (threadIdx.x < 8)
        pprob[(long)blockIdx.x * 8 + threadIdx.x] =
            pp[0][threadIdx.x] + pp[1][threadIdx.x] + pp[2][threadIdx.x] + pp[3][threadIdx.x];
}

// ---------- routing: desc[] round-robin over experts (XCD affinity) ----------
__global__ __launch_bounds__(256) void k_route(const int* __restrict__ topidx,
    int* __restrict__ rowidx, int* __restrict__ invpos,
    int* __restrict__ ntiles, Desc* __restrict__ desc, int* __restrict__ cnt)
{
    __shared__ int cnt_s[8], base_s[8], fill[8];
    const int tid = threadIdx.x;
    if (tid < 8) { cnt_s[tid] = 0; fill[tid] = 0; }
    __syncthreads();
    for (int i = tid; i < 4096; i += 256)
        atomicAdd(&cnt_s[topidx[i]], 1);
    __syncthreads();
    if (tid == 0) {
        int tl[8]; int running = 0, maxT = 0;
        for (int e = 0; e < 8; ++e) {
            int ce = cnt_s[e];
            cnt[e] = ce;
            base_s[e] = running;
            tl[e] = (ce + 127) >> 7;
            running += tl[e] * 128;
            if (tl[e] > maxT) maxT = tl[e];
        }
        int nt = 0;
        for (int r = 0; r < maxT; ++r)
            for (int e = 0; e < 8; ++e)
                if (r < tl[e]) {
                    desc[nt].e = e;
                    desc[nt].base = base_s[e] + r * 128;
                    desc[nt].rows = min(128, cnt_s[e] - r * 128);
                    ++nt;
                }
        *ntiles = nt;
    }
    __syncthreads();
    for (int t = tid; t < 2048; t += 256) {
#pragma unroll
        for (int s = 0; s < 2; ++s) {
            int e = topidx[t * 2 + s];
            int p = base_s[e] + atomicAdd(&fill[e], 1);
            rowidx[p] = t;
            invpos[t * 2 + s] = p;
        }
    }
}

// ---------- combine ----------
__global__ __launch_bounds__(256) void k_combine(const float* __restrict__ x1,
    const float* __restrict__ eo, const int* __restrict__ invpos,
    const float* __restrict__ gates, float* __restrict__ out)
{
    const int t = blockIdx.x, c = threadIdx.x * 4;
    float g0 = gates[t * 2], g1 = gates[t * 2 + 1];
    int p0 = invpos[t * 2], p1 = invpos[t * 2 + 1];
    float4 xv = *(const float4*)(x1 + (long)t * 1024 + c);
    float4 e0 = *(const float4*)(eo + (long)p0 * 1024 + c);
    float4 e1 = *(const float4*)(eo + (long)p1 * 1024 + c);
    float4 o;
    o.x = xv.x + g0 * e0.x + g1 * e1.x;
    o.y = xv.y + g0 * e0.y + g1 * e1.y;
    o.z = xv.z + g0 * e0.z + g1 * e1.z;
    o.w = xv.w + g0 * e0.w + g1 * e1.w;
    *(float4*)(out + (long)t * 1024 + c) = o;
}

// ---------- loss ----------
__global__ __launch_bounds__(256) void k_loss(const int* __restrict__ cnt,
    const float* __restrict__ pprob, float* __restrict__ out)
{
    __shared__ float m[32][8];
    const int tid = threadIdx.x;
    const int e = tid & 7, g = tid >> 3;
    float local = 0.0f;
    for (int b = g; b < 512; b += 32) local += pprob[b * 8 + e];
    m[g][e] = local;
    __syncthreads();
    if (tid == 0) {
        float us = 0, ps = 0, pe[8], ue[8];
        for (int ee = 0; ee < 8; ++ee) {
            float s = 0;
            for (int gg = 0; gg < 32; ++gg) s += m[gg][ee];
            pe[ee] = s; ps += s;
            ue[ee] = (float)cnt[ee]; us += ue[ee];
        }
        float lb = 0;
        for (int ee = 0; ee < 8; ++ee) lb += (ue[ee] / us) * (pe[ee] / ps);
        out[2097152] = lb * 8.0f;
    }
}

// =====================  launch  =====================
extern "C" void kernel_launch(void* const* d_in, const int* in_sizes, int n_in,
                              void* d_out, int out_size, void* d_ws, size_t ws_size,
                              hipStream_t stream)
{
    const float* x    = (const float*)d_in[0];
    const float* ln1g = (const float*)d_in[1];
    const float* ln1b = (const float*)d_in[2];
    const float* qkvw = (const float*)d_in[3];
    const float* outw = (const float*)d_in[4];
    const float* ln2g = (const float*)d_in[5];
    const float* ln2b = (const float*)d_in[6];
    const float* gw   = (const float*)d_in[7];
    const float* eb   = (const float*)d_in[8];
    const float* w1   = (const float*)d_in[9];
    const float* w2   = (const float*)d_in[10];
    float* out = (float*)d_out;
    char* ws = (char*)d_ws;

    // workspace map (bytes), total ~222 MB
    constexpr size_t OFF_QWTH = 0;          // half [3072][1024]
    constexpr size_t OFF_QWTL = 6291456;
    constexpr size_t OFF_OWTH = 12582912;   // half [1024][1024]
    constexpr size_t OFF_OWTL = 14680064;
    constexpr size_t OFF_XN1H = 16777216;   // half [2048][1024]; head doubles as zero page post-QKV
    constexpr size_t OFF_XN1L = 20971520;
    constexpr size_t OFF_QH   = 25165824;   // half [32][1024][64]
    constexpr size_t OFF_QL   = 29360128;
    constexpr size_t OFF_KH   = 33554432;
    constexpr size_t OFF_KL   = 37748736;
    constexpr size_t OFF_VTH  = 41943040;   // half [32][64][1024]
    constexpr size_t OFF_VTL  = 46137344;
    constexpr size_t OFF_OH   = 50331648;   // half [2048][1024]
    constexpr size_t OFF_OL   = 54525952;
    constexpr size_t OFF_X1   = 58720256;   // f32 [2048][1024]
    constexpr size_t OFF_XN2F = 67108864;   // f32
    constexpr size_t OFF_XN2H = 75497472;   // half
    constexpr size_t OFF_RC   = 79691776;   // f32 [1024][32]
    constexpr size_t OFF_RS   = 79822848;
    constexpr size_t OFF_IDX  = 79953920;   // int [2048][2]
    constexpr size_t OFF_GATES= 79970304;   // f32 [2048][2]
    constexpr size_t OFF_INVP = 79986688;   // int [2048][2]
    constexpr size_t OFF_ROWI = 80003072;   // int [5120]
    constexpr size_t OFF_CNT  = 80023552;   // int [8]
    constexpr size_t OFF_NT   = 80023616;   // int
    constexpr size_t OFF_DESC = 80023680;   // Desc [40]
    constexpr size_t OFF_PPROB= 80024704;   // f32 [512][8]
    constexpr size_t OFF_ACT  = 80041984;   // half [5120][2048]
    constexpr size_t OFF_EO   = 101013504;  // f32 [5120][1024]
    constexpr size_t OFF_W1T  = 121985024;  // half [8][4096][1024]
    constexpr size_t OFF_W2T  = 189093888;  // half [8][1024][2048]

    __half* qwth = (__half*)(ws + OFF_QWTH);
    __half* qwtl = (__half*)(ws + OFF_QWTL);
    __half* owth = (__half*)(ws + OFF_OWTH);
    __half* owtl = (__half*)(ws + OFF_OWTL);
    __half* xn1h = (__half*)(ws + OFF_XN1H);
    __half* xn1l = (__half*)(ws + OFF_XN1L);
    __half* qh   = (__half*)(ws + OFF_QH);
    __half* ql   = (__half*)(ws + OFF_QL);
    __half* kh   = (__half*)(ws + OFF_KH);
    __half* kl   = (__half*)(ws + OFF_KL);
    __half* vth  = (__half*)(ws + OFF_VTH);
    __half* vtl  = (__half*)(ws + OFF_VTL);
    __half* oh   = (__half*)(ws + OFF_OH);
    __half* ol   = (__half*)(ws + OFF_OL);
    float* x1    = (float*)(ws + OFF_X1);
    float* xn2f  = (float*)(ws + OFF_XN2F);
    __half* xn2h = (__half*)(ws + OFF_XN2H);
    float* rc    = (float*)(ws + OFF_RC);
    float* rs    = (float*)(ws + OFF_RS);
    int*   idx   = (int*)(ws + OFF_IDX);
    float* gates = (float*)(ws + OFF_GATES);
    int*   invp  = (int*)(ws + OFF_INVP);
    int*   rowi  = (int*)(ws + OFF_ROWI);
    int*   cnt   = (int*)(ws + OFF_CNT);
    int*   nt    = (int*)(ws + OFF_NT);
    Desc*  desc  = (Desc*)(ws + OFF_DESC);
    float* pprob = (float*)(ws + OFF_PPROB);
    __half* act  = (__half*)(ws + OFF_ACT);
    float* eo    = (float*)(ws + OFF_EO);
    __half* w1t  = (__half*)(ws + OFF_W1T);
    __half* w2t  = (__half*)(ws + OFF_W2T);
    __half* zp   = xn1h;                    // zero page (xn1 dead after QKV GEMM)

    // weight transposes -> split planes (attention) / plain fp16 (MoE)
    k_transpose_pk<<<dim3(48, 16, 1), 256, 0, stream>>>(qkvw, qwth, qwtl, 1024, 3072);
    k_transpose_pk<<<dim3(16, 16, 1), 256, 0, stream>>>(outw, owth, owtl, 1024, 1024);
    k_wconv<<<dim3(64, 16, 8), 256, 0, stream>>>(w1, w1t, 1024, 4096);
    k_wconv<<<dim3(16, 32, 8), 256, 0, stream>>>(w2, w2t, 2048, 1024);
    k_rope_table<<<dim3(128), 256, 0, stream>>>(rc, rs);

    // LN1 -> xn1 planes
    k_ln<0><<<dim3(2048), 256, 0, stream>>>(x, ln1g, ln1b, xn1h, xn1l);

    // QKV GEMM with fused RoPE + q/k/v scatter (64x128 tiles, 768 blocks)
    k_gemm_pk<2, 2, 2, 4, EPI_QKV><<<dim3(32, 24, 1), 256, 0, stream>>>(
        xn1h, xn1l, 1024, qwth, qwtl, 1024, nullptr, 0, 2048, 3072, 1024,
        nullptr, qh, ql, kh, kl, vth, vtl, rc, rs);

    // xn1 now dead -> zero its head for the MoE gather pad page
    hipMemsetAsync(zp, 0, 4096, stream);

    // flash attention -> o planes
    k_flash<<<dim3(16, 32, 1), 256, 0, stream>>>(qh, ql, kh, kl, vth, vtl, oh, ol);

    // x1 = x + o @ out_w
    k_gemm_pk<2, 2, 2, 2, EPI_RESID><<<dim3(32, 16, 1), 256, 0, stream>>>(
        oh, ol, 1024, owth, owtl, 1024, x1, 1024, 2048, 1024, 1024,
        x, nullptr, nullptr, nullptr, nullptr, nullptr, nullptr, nullptr, nullptr);

    // LN2 -> xn2 (f32 for gating, fp16 for MoE)
    k_ln<1><<<dim3(2048), 256, 0, stream>>>(x1, ln2g, ln2b, xn2f, xn2h);

    // gating + routing
    k_gate<<<dim3(512), 256, 0, stream>>>(xn2f, gw, eb, idx, gates, pprob);
    k_route<<<dim3(1), 256, 0, stream>>>(idx, rowi, invp, nt, desc, cnt);

    // MoE GEMM1: act = silu(h1)*h2, 128x128 tiles, 2-phase dbuf DMA staging
    k_gemm_moe<true, 0, 4, 4, 2><<<dim3(40, 32, 1), 256, 0, stream>>>(
        xn2h, 1024, rowi, desc, nt, w1t, 4194304, 1024, act, 1024, zp);

    // MoE GEMM2: eo = act @ w2[e], 128x64 tiles, 2-phase dbuf DMA staging
    k_gemm_moe<false, 1, 2, 4, 1><<<dim3(40, 16, 1), 256, 0, stream>>>(
        act, 2048, nullptr, desc, nt, w2t, 2097152, 2048, eo, 2048, zp);

    // combine + loss
    k_combine<<<dim3(2048), 256, 0, stream>>>(x1, eo, invp, gates, out);
    k_loss<<<dim3(1), 256, 0, stream>>>(cnt, pprob, out);
}